// Round 6
// baseline (436.711 us; speedup 1.0000x reference)
//
#include <hip/hip_runtime.h>
#include <math.h>

#define N_NODES 50000
#define F_IN    128
#define HIDC    64
#define HEADS   4
#define C1      (HEADS*HIDC)   // 256
#define F_OUT   128
#define NE      800000
#define NET     (NE + N_NODES) // 850000 edges incl self-loops
#define NEG_SLOPE 0.2f
#define SCAN_NBLKS ((N_NODES + 255) / 256)   // 196
#define NHALF (N_NODES / 2)

typedef unsigned short ushort_t;
typedef __attribute__((ext_vector_type(8))) short bf16x8;
typedef __attribute__((ext_vector_type(8))) unsigned short us8;
typedef __attribute__((ext_vector_type(4))) float f32x4;

__device__ __forceinline__ float b2f(ushort_t x) {
  return __uint_as_float(((unsigned int)x) << 16);
}
__device__ __forceinline__ ushort_t f2bf(float f) {  // RNE, no NaN expected
  unsigned int u = __float_as_uint(f);
  return (ushort_t)((u + 0x7fffu + ((u >> 16) & 1u)) >> 16);
}

// ---------------- CSR build ----------------

__global__ void count_deg(const int* __restrict__ ei, int* __restrict__ deg) {
  int e = blockIdx.x * blockDim.x + threadIdx.x;
  if (e >= NET) return;
  int d = (e < NE) ? ei[NE + e] : (e - NE);
  atomicAdd(&deg[d], 1);
}

__global__ __launch_bounds__(256) void scan_blocks(const int* __restrict__ deg,
                                                   int* __restrict__ tmp,
                                                   int* __restrict__ bsum) {
  __shared__ int sh[256];
  int b = blockIdx.x, t = threadIdx.x;
  int idx = b * 256 + t;
  sh[t] = (idx < N_NODES) ? deg[idx] : 0;
  __syncthreads();
#pragma unroll
  for (int off = 1; off < 256; off <<= 1) {
    int u = (t >= off) ? sh[t - off] : 0;
    __syncthreads();
    sh[t] += u;
    __syncthreads();
  }
  if (idx < N_NODES) tmp[idx] = sh[t];
  if (t == 255) bsum[b] = sh[255];
}

__global__ __launch_bounds__(256) void scan_bsum(int* __restrict__ bsum) {
  __shared__ int sh[256];
  int t = threadIdx.x;
  sh[t] = (t < SCAN_NBLKS) ? bsum[t] : 0;
  __syncthreads();
#pragma unroll
  for (int off = 1; off < 256; off <<= 1) {
    int u = (t >= off) ? sh[t - off] : 0;
    __syncthreads();
    sh[t] += u;
    __syncthreads();
  }
  if (t < SCAN_NBLKS) bsum[t] = sh[t];
}

__global__ __launch_bounds__(256) void finalize_rowptr(const int* __restrict__ tmp,
                                                       const int* __restrict__ bsum,
                                                       int* __restrict__ rowptr) {
  int b = blockIdx.x;
  int idx = b * 256 + threadIdx.x;
  if (idx == 0) rowptr[0] = 0;
  if (idx < N_NODES) {
    int off = (b == 0) ? 0 : bsum[b - 1];
    rowptr[idx + 1] = tmp[idx] + off;
  }
}

__global__ void scatter_edges(const int* __restrict__ ei, const int* __restrict__ rowptr,
                              int* __restrict__ fill, int* __restrict__ colsrc,
                              int* __restrict__ coldst) {
  int e = blockIdx.x * blockDim.x + threadIdx.x;
  if (e >= NET) return;
  int s, d;
  if (e < NE) { s = ei[e]; d = ei[NE + e]; }
  else        { s = e - NE; d = s; }
  int pos = atomicAdd(&fill[d], 1);
  int slot = rowptr[d] + pos;
  colsrc[slot] = s;
  coldst[slot] = d;
}

// ---------------- setup: bf16 casts / weight transposes ----------------

__global__ void cast_x(const float* __restrict__ X, ushort_t* __restrict__ Xb) {
  int i = blockIdx.x * blockDim.x + threadIdx.x;
  if (i * 4 >= N_NODES * F_IN) return;
  float4 v = *(const float4*)&X[i * 4];
  ushort4 o;
  o.x = f2bf(v.x); o.y = f2bf(v.y); o.z = f2bf(v.z); o.w = f2bf(v.w);
  *(ushort4*)&Xb[i * 4] = o;
}

template<int K, int NCOL>
__global__ void transpose_w(const float* __restrict__ W, ushort_t* __restrict__ Wt) {
  int idx = blockIdx.x * blockDim.x + threadIdx.x;
  if (idx >= K * NCOL) return;
  int k = idx / NCOL, n = idx - k * NCOL;
  Wt[(size_t)n * K + k] = f2bf(W[idx]);
}

// ---------------- MFMA bf16 GEMM: C = A @ Bt^T, slice-planar C output ----------------
// C stored as NCOL/32 planes of [N_NODES][32] bf16 (64B rows -> 3.2MB planes, L2-fit).

#define BKS 64
#define LDT 72

template<int K, int NCOL>
__global__ __launch_bounds__(256) void gemm_mfma(const ushort_t* __restrict__ A,
                                                 const ushort_t* __restrict__ Bt,
                                                 ushort_t* __restrict__ C) {
  __shared__ __align__(16) char smem[2 * 128 * LDT * 2];
  ushort_t (*Asl)[LDT] = (ushort_t(*)[LDT])smem;
  ushort_t (*Bsl)[LDT] = (ushort_t(*)[LDT])(smem + 128 * LDT * 2);
  ushort_t (*Ep)[136]  = (ushort_t(*)[136])smem;

  const int tid = threadIdx.x;
  const int lane = tid & 63;
  const int wave = tid >> 6;
  const int wr = wave >> 1, wc = wave & 1;
  const int row0 = blockIdx.y * 128;
  const int col0 = blockIdx.x * 128;
  const int l15 = lane & 15, l4 = lane >> 4;

  f32x4 acc[4][4] = {};

  for (int k0 = 0; k0 < K; k0 += BKS) {
#pragma unroll
    for (int i = 0; i < 4; ++i) {
      int seg = tid + i * 256;
      int row = seg >> 3, kq = (seg & 7) * 8;
      int arow = row0 + row;
      us8 v = {0, 0, 0, 0, 0, 0, 0, 0};
      if (arow < N_NODES) v = *(const us8*)&A[(size_t)arow * K + k0 + kq];
      *(us8*)&Asl[row][kq] = v;
    }
#pragma unroll
    for (int i = 0; i < 4; ++i) {
      int seg = tid + i * 256;
      int row = seg >> 3, kq = (seg & 7) * 8;
      us8 v = *(const us8*)&Bt[(size_t)(col0 + row) * K + k0 + kq];
      *(us8*)&Bsl[row][kq] = v;
    }
    __syncthreads();
#pragma unroll
    for (int kk = 0; kk < BKS; kk += 32) {
      bf16x8 af[4], bfr[4];
#pragma unroll
      for (int mi = 0; mi < 4; ++mi)
        af[mi] = *(const bf16x8*)&Asl[wr * 64 + mi * 16 + l15][kk + l4 * 8];
#pragma unroll
      for (int ni = 0; ni < 4; ++ni)
        bfr[ni] = *(const bf16x8*)&Bsl[wc * 64 + ni * 16 + l15][kk + l4 * 8];
#pragma unroll
      for (int mi = 0; mi < 4; ++mi)
#pragma unroll
        for (int ni = 0; ni < 4; ++ni)
          acc[mi][ni] = __builtin_amdgcn_mfma_f32_16x16x32_bf16(af[mi], bfr[ni], acc[mi][ni], 0, 0, 0);
    }
    __syncthreads();
  }

#pragma unroll
  for (int mi = 0; mi < 4; ++mi)
#pragma unroll
    for (int ni = 0; ni < 4; ++ni)
#pragma unroll
      for (int r = 0; r < 4; ++r)
        Ep[wr * 64 + mi * 16 + l4 * 4 + r][wc * 64 + ni * 16 + l15] = f2bf(acc[mi][ni][r]);
  __syncthreads();
  {
    int row = tid >> 1, half = tid & 1;
    int grow = row0 + row;
    if (grow < N_NODES) {
#pragma unroll
      for (int i = 0; i < 8; ++i) {
        int c0 = col0 + half * 64 + i * 8;       // global channel base of this 8-chunk
        int p = c0 >> 5;                          // slice plane
        *(us8*)&C[(size_t)p * N_NODES * 32 + (size_t)grow * 32 + (c0 & 31)] =
            *(const us8*)&Ep[row][half * 64 + i * 8];
      }
    }
  }
}

// ---------------- attention logits (slice-planar H) ----------------

__global__ __launch_bounds__(256) void al_heads_p(const ushort_t* __restrict__ Hs,
                                                  const float* __restrict__ a_s,
                                                  const float* __restrict__ a_d,
                                                  float* __restrict__ als,
                                                  float* __restrict__ ald) {
  int n = blockIdx.x;
  int tid = threadIdx.x;
  int h = tid >> 6, lane = tid & 63;
  float v = b2f(Hs[(size_t)(tid >> 5) * N_NODES * 32 + (size_t)n * 32 + (tid & 31)]);
  float ps = v * a_s[tid], pd = v * a_d[tid];
#pragma unroll
  for (int off = 32; off; off >>= 1) {
    ps += __shfl_down(ps, off, 64);
    pd += __shfl_down(pd, off, 64);
  }
  if (lane == 0) { als[n * HEADS + h] = ps; ald[n * HEADS + h] = pd; }
}

__global__ __launch_bounds__(256) void al_single_p(const ushort_t* __restrict__ Hs,
                                                   const float* __restrict__ a_s,
                                                   const float* __restrict__ a_d,
                                                   float* __restrict__ als,
                                                   float* __restrict__ ald) {
  int wave = threadIdx.x >> 6, lane = threadIdx.x & 63;
  int n = blockIdx.x * 4 + wave;
  if (n >= N_NODES) return;
  size_t ro = (size_t)n * 32 + (lane & 31);
  float v0 = b2f(Hs[(size_t)(lane >> 5) * N_NODES * 32 + ro]);        // ch lane
  float v1 = b2f(Hs[(size_t)(2 + (lane >> 5)) * N_NODES * 32 + ro]);  // ch 64+lane
  float ps = v0 * a_s[lane] + v1 * a_s[64 + lane];
  float pd = v0 * a_d[lane] + v1 * a_d[64 + lane];
#pragma unroll
  for (int off = 32; off; off >>= 1) {
    ps += __shfl_down(ps, off, 64);
    pd += __shfl_down(pd, off, 64);
  }
  if (lane == 0) { als[n] = ps; ald[n] = pd; }
}

// ---------------- edge-parallel softmax numerators (P1 head-planar) ----------------

__global__ void scores1(const int* __restrict__ colsrc, const int* __restrict__ coldst,
                        const float* __restrict__ als, const float* __restrict__ ald,
                        float* __restrict__ P) {
  int i = blockIdx.x * blockDim.x + threadIdx.x;
  if (i >= NET) return;
  int s = colsrc[i], d = coldst[i];
  float4 as = *(const float4*)&als[s * 4];
  float4 ad = *(const float4*)&ald[d * 4];
  float sc;
  sc = as.x + ad.x; sc = sc > 0.f ? sc : NEG_SLOPE * sc; P[0 * (size_t)NET + i] = __expf(sc);
  sc = as.y + ad.y; sc = sc > 0.f ? sc : NEG_SLOPE * sc; P[1 * (size_t)NET + i] = __expf(sc);
  sc = as.z + ad.z; sc = sc > 0.f ? sc : NEG_SLOPE * sc; P[2 * (size_t)NET + i] = __expf(sc);
  sc = as.w + ad.w; sc = sc > 0.f ? sc : NEG_SLOPE * sc; P[3 * (size_t)NET + i] = __expf(sc);
}

__global__ void scores2(const int* __restrict__ colsrc, const int* __restrict__ coldst,
                        const float* __restrict__ als, const float* __restrict__ ald,
                        float* __restrict__ P) {
  int i = blockIdx.x * blockDim.x + threadIdx.x;
  if (i >= NET) return;
  float sc = als[colsrc[i]] + ald[coldst[i]];
  sc = sc > 0.f ? sc : NEG_SLOPE * sc;
  P[i] = __expf(sc);
}

// ---------------- per-node denominators (inverse) ----------------

__global__ __launch_bounds__(256) void norm1(const int* __restrict__ rowptr,
                                             const float* __restrict__ P,
                                             float* __restrict__ sinv) {
  int wave = threadIdx.x >> 6, lane = threadIdx.x & 63;
  int n = blockIdx.x * 4 + wave;
  if (n >= N_NODES) return;
  int beg = rowptr[n], end = rowptr[n + 1];
  float s0 = 0.f, s1 = 0.f, s2 = 0.f, s3 = 0.f;
  for (int i = beg + lane; i < end; i += 64) {
    s0 += P[0 * (size_t)NET + i];
    s1 += P[1 * (size_t)NET + i];
    s2 += P[2 * (size_t)NET + i];
    s3 += P[3 * (size_t)NET + i];
  }
#pragma unroll
  for (int off = 32; off; off >>= 1) {
    s0 += __shfl_down(s0, off, 64);
    s1 += __shfl_down(s1, off, 64);
    s2 += __shfl_down(s2, off, 64);
    s3 += __shfl_down(s3, off, 64);
  }
  if (lane == 0) {
    float4 r = make_float4(1.f / s0, 1.f / s1, 1.f / s2, 1.f / s3);
    *(float4*)&sinv[n * 4] = r;
  }
}

__global__ __launch_bounds__(256) void norm2(const int* __restrict__ rowptr,
                                             const float* __restrict__ P,
                                             float* __restrict__ sinv) {
  int wave = threadIdx.x >> 6, lane = threadIdx.x & 63;
  int n = blockIdx.x * 4 + wave;
  if (n >= N_NODES) return;
  int beg = rowptr[n], end = rowptr[n + 1];
  float s = 0.f;
  for (int i = beg + lane; i < end; i += 64) s += P[i];
#pragma unroll
  for (int off = 32; off; off >>= 1) s += __shfl_down(s, off, 64);
  if (lane == 0) sinv[n] = 1.f / s;
}

// ---------------- XCD-sliced gather aggregation ----------------
// bid = node_blk*8 + g; round-robin dispatch puts all blocks with the same g on
// one XCD, whose 4MB L2 then holds that slice's 3.2MB H-plane -> gathers hit L2.
// Wave per node; 4-lane groups, 16 edges in flight; us8 (16B) loads.

__global__ __launch_bounds__(256) void agg1_slice(const int* __restrict__ rowptr,
                                                  const int* __restrict__ colsrc,
                                                  const ushort_t* __restrict__ Hs,
                                                  const float* __restrict__ P,
                                                  const float* __restrict__ sinv,
                                                  const float* __restrict__ b1,
                                                  ushort_t* __restrict__ X2b) {
  int bid = blockIdx.x;
  int s = bid & 7;              // slice == target XCD
  int nblk = bid >> 3;
  int wave = threadIdx.x >> 6, lane = threadIdx.x & 63;
  int n = nblk * 4 + wave;
  if (n >= N_NODES) return;
  int h = s >> 1;               // head of this slice
  int eg = lane >> 2, lo = lane & 3;
  const ushort_t* __restrict__ plane = Hs + (size_t)s * N_NODES * 32;
  const float* __restrict__ Ph = P + (size_t)h * NET;
  int beg = rowptr[n], end = rowptr[n + 1];
  float a[8] = {};
  for (int i = beg + eg; i < end; i += 16) {
    int src = colsrc[i];
    float w = Ph[i];
    us8 v = *(const us8*)&plane[(size_t)src * 32 + lo * 8];
#pragma unroll
    for (int j = 0; j < 8; ++j) a[j] = fmaf(w, b2f((ushort_t)v[j]), a[j]);
  }
#pragma unroll
  for (int m = 4; m < 64; m <<= 1)
#pragma unroll
    for (int j = 0; j < 8; ++j) a[j] += __shfl_xor(a[j], m);
  if (lane < 4) {
    float si = sinv[n * 4 + h];
    int c = s * 32 + lo * 8;
    ushort_t o[8];
#pragma unroll
    for (int j = 0; j < 8; ++j) o[j] = f2bf(fmaxf(a[j] * si + b1[c + j], 0.f));
    *(us8*)&X2b[(size_t)n * C1 + c] = *(const us8*)o;
  }
}

// layer2: 4 slices x 2 node-halves over 8 XCDs.
__global__ __launch_bounds__(256) void agg2_slice(const int* __restrict__ rowptr,
                                                  const int* __restrict__ colsrc,
                                                  const ushort_t* __restrict__ Hs,
                                                  const float* __restrict__ P,
                                                  const float* __restrict__ sinv,
                                                  const float* __restrict__ b2,
                                                  float* __restrict__ out) {
  int bid = blockIdx.x;
  int g = bid & 7;
  int s = g >> 1;               // slice plane (0..3)
  int halfsel = g & 1;
  int nblk = bid >> 3;
  int wave = threadIdx.x >> 6, lane = threadIdx.x & 63;
  int n0 = nblk * 4 + wave;
  if (n0 >= NHALF) return;
  int n = halfsel * NHALF + n0;
  int eg = lane >> 2, lo = lane & 3;
  const ushort_t* __restrict__ plane = Hs + (size_t)s * N_NODES * 32;
  int beg = rowptr[n], end = rowptr[n + 1];
  float a[8] = {};
  for (int i = beg + eg; i < end; i += 16) {
    int src = colsrc[i];
    float w = P[i];
    us8 v = *(const us8*)&plane[(size_t)src * 32 + lo * 8];
#pragma unroll
    for (int j = 0; j < 8; ++j) a[j] = fmaf(w, b2f((ushort_t)v[j]), a[j]);
  }
#pragma unroll
  for (int m = 4; m < 64; m <<= 1)
#pragma unroll
    for (int j = 0; j < 8; ++j) a[j] += __shfl_xor(a[j], m);
  if (lane < 4) {
    float si = sinv[n];
    int c = s * 32 + lo * 8;
    float4 o0, o1;
    o0.x = a[0] * si + b2[c + 0]; o0.y = a[1] * si + b2[c + 1];
    o0.z = a[2] * si + b2[c + 2]; o0.w = a[3] * si + b2[c + 3];
    o1.x = a[4] * si + b2[c + 4]; o1.y = a[5] * si + b2[c + 5];
    o1.z = a[6] * si + b2[c + 6]; o1.w = a[7] * si + b2[c + 7];
    *(float4*)&out[(size_t)n * F_OUT + c] = o0;
    *(float4*)&out[(size_t)n * F_OUT + c + 4] = o1;
  }
}

// ---------------- launch ----------------

extern "C" void kernel_launch(void* const* d_in, const int* in_sizes, int n_in,
                              void* d_out, int out_size, void* d_ws, size_t ws_size,
                              hipStream_t stream) {
  const float* X   = (const float*)d_in[0];
  const int*   EI  = (const int*)d_in[1];
  const float* W1  = (const float*)d_in[2];
  const float* a1s = (const float*)d_in[3];
  const float* a1d = (const float*)d_in[4];
  const float* b1  = (const float*)d_in[5];
  const float* W2  = (const float*)d_in[6];
  const float* a2s = (const float*)d_in[7];
  const float* a2d = (const float*)d_in[8];
  const float* b2  = (const float*)d_in[9];
  float* out = (float*)d_out;

  char* ws = (char*)d_ws;
  size_t off = 0;
  auto alloc = [&](size_t bytes) -> void* {
    void* p = ws + off;
    off += (bytes + 255) & ~(size_t)255;
    return p;
  };
  int* deg        = (int*)alloc((size_t)N_NODES * 4);
  int* fill       = (int*)alloc((size_t)N_NODES * 4);
  int* rowptr     = (int*)alloc((size_t)(N_NODES + 1) * 4);
  int* scantmp    = (int*)alloc((size_t)N_NODES * 4);
  int* bsum       = (int*)alloc((size_t)SCAN_NBLKS * 4);
  int* colsrc     = (int*)alloc((size_t)NET * 4);
  int* coldst     = (int*)alloc((size_t)NET * 4);
  ushort_t* Xb    = (ushort_t*)alloc((size_t)N_NODES * F_IN * 2);
  ushort_t* W1t   = (ushort_t*)alloc((size_t)C1 * F_IN * 2);
  ushort_t* W2t   = (ushort_t*)alloc((size_t)F_OUT * C1 * 2);
  ushort_t* H1s   = (ushort_t*)alloc((size_t)N_NODES * C1 * 2);   // 8 planes [N][32]
  float* ALS1     = (float*)alloc((size_t)N_NODES * HEADS * 4);
  float* ALD1     = (float*)alloc((size_t)N_NODES * HEADS * 4);
  float* SINV1    = (float*)alloc((size_t)N_NODES * HEADS * 4);
  float* P1       = (float*)alloc((size_t)NET * HEADS * 4);       // head-planar
  ushort_t* X2b   = (ushort_t*)alloc((size_t)N_NODES * C1 * 2);   // row-major (gemm2 A)
  float* ALS2     = (float*)alloc((size_t)N_NODES * 4);
  float* ALD2     = (float*)alloc((size_t)N_NODES * 4);
  float* SINV2    = (float*)alloc((size_t)N_NODES * 4);
  float* P2       = (float*)alloc((size_t)NET * 4);
  ushort_t* H2s = H1s;  // H1 planes dead after agg1

  hipMemsetAsync(deg, 0, (size_t)N_NODES * 4, stream);
  hipMemsetAsync(fill, 0, (size_t)N_NODES * 4, stream);

  // CSR build
  count_deg<<<(NET + 255) / 256, 256, 0, stream>>>(EI, deg);
  scan_blocks<<<SCAN_NBLKS, 256, 0, stream>>>(deg, scantmp, bsum);
  scan_bsum<<<1, 256, 0, stream>>>(bsum);
  finalize_rowptr<<<SCAN_NBLKS, 256, 0, stream>>>(scantmp, bsum, rowptr);
  scatter_edges<<<(NET + 255) / 256, 256, 0, stream>>>(EI, rowptr, fill, colsrc, coldst);

  // setup casts/transposes
  cast_x<<<(N_NODES * F_IN / 4 + 255) / 256, 256, 0, stream>>>(X, Xb);
  transpose_w<F_IN, C1><<<(F_IN * C1 + 255) / 256, 256, 0, stream>>>(W1, W1t);
  transpose_w<C1, F_OUT><<<(C1 * F_OUT + 255) / 256, 256, 0, stream>>>(W2, W2t);

  // layer 1
  {
    dim3 grid(C1 / 128, (N_NODES + 127) / 128);
    gemm_mfma<F_IN, C1><<<grid, 256, 0, stream>>>(Xb, W1t, H1s);
  }
  al_heads_p<<<N_NODES, 256, 0, stream>>>(H1s, a1s, a1d, ALS1, ALD1);
  scores1<<<(NET + 255) / 256, 256, 0, stream>>>(colsrc, coldst, ALS1, ALD1, P1);
  norm1<<<(N_NODES + 3) / 4, 256, 0, stream>>>(rowptr, P1, SINV1);
  agg1_slice<<<((N_NODES + 3) / 4) * 8, 256, 0, stream>>>(rowptr, colsrc, H1s, P1, SINV1, b1, X2b);

  // layer 2
  {
    dim3 grid(F_OUT / 128, (N_NODES + 127) / 128);
    gemm_mfma<C1, F_OUT><<<grid, 256, 0, stream>>>(X2b, W2t, H2s);
  }
  al_single_p<<<(N_NODES + 3) / 4, 256, 0, stream>>>(H2s, a2s, a2d, ALS2, ALD2);
  scores2<<<(NET + 255) / 256, 256, 0, stream>>>(colsrc, coldst, ALS2, ALD2, P2);
  norm2<<<(N_NODES + 3) / 4, 256, 0, stream>>>(rowptr, P2, SINV2);
  agg2_slice<<<((NHALF + 3) / 4) * 8, 256, 0, stream>>>(rowptr, colsrc, H2s, P2, SINV2, b2, out);
}

// Round 7
// 284.633 us; speedup vs baseline: 1.5343x; 1.5343x over previous
//
#include <hip/hip_runtime.h>
#include <math.h>

#define N_NODES 50000
#define F_IN    128
#define HIDC    64
#define HEADS   4
#define C1      (HEADS*HIDC)   // 256
#define F_OUT   128
#define NE      800000
#define NET     (NE + N_NODES) // 850000 edges incl self-loops
#define NEG_SLOPE 0.2f
#define SCAN_NBLKS ((N_NODES + 255) / 256)   // 196

typedef unsigned short ushort_t;
typedef __attribute__((ext_vector_type(8))) short bf16x8;
typedef __attribute__((ext_vector_type(8))) unsigned short us8;
typedef __attribute__((ext_vector_type(4))) float f32x4;

__device__ __forceinline__ float b2f(ushort_t x) {
  return __uint_as_float(((unsigned int)x) << 16);
}
__device__ __forceinline__ ushort_t f2bf(float f) {  // RNE, no NaN expected
  unsigned int u = __float_as_uint(f);
  return (ushort_t)((u + 0x7fffu + ((u >> 16) & 1u)) >> 16);
}
// bf16-pair unpack from one u32 (little-endian: low 16 bits = even channel)
__device__ __forceinline__ float u2f_lo(unsigned int u) { return __uint_as_float(u << 16); }
__device__ __forceinline__ float u2f_hi(unsigned int u) { return __uint_as_float(u & 0xffff0000u); }

// ---------------- CSR build ----------------

__global__ void count_deg(const int* __restrict__ ei, int* __restrict__ deg) {
  int e = blockIdx.x * blockDim.x + threadIdx.x;
  if (e >= NET) return;
  int d = (e < NE) ? ei[NE + e] : (e - NE);
  atomicAdd(&deg[d], 1);
}

__global__ __launch_bounds__(256) void scan_blocks(const int* __restrict__ deg,
                                                   int* __restrict__ tmp,
                                                   int* __restrict__ bsum) {
  __shared__ int sh[256];
  int b = blockIdx.x, t = threadIdx.x;
  int idx = b * 256 + t;
  sh[t] = (idx < N_NODES) ? deg[idx] : 0;
  __syncthreads();
#pragma unroll
  for (int off = 1; off < 256; off <<= 1) {
    int u = (t >= off) ? sh[t - off] : 0;
    __syncthreads();
    sh[t] += u;
    __syncthreads();
  }
  if (idx < N_NODES) tmp[idx] = sh[t];
  if (t == 255) bsum[b] = sh[255];
}

__global__ __launch_bounds__(256) void scan_bsum(int* __restrict__ bsum) {
  __shared__ int sh[256];
  int t = threadIdx.x;
  sh[t] = (t < SCAN_NBLKS) ? bsum[t] : 0;
  __syncthreads();
#pragma unroll
  for (int off = 1; off < 256; off <<= 1) {
    int u = (t >= off) ? sh[t - off] : 0;
    __syncthreads();
    sh[t] += u;
    __syncthreads();
  }
  if (t < SCAN_NBLKS) bsum[t] = sh[t];
}

__global__ __launch_bounds__(256) void finalize_rowptr(const int* __restrict__ tmp,
                                                       const int* __restrict__ bsum,
                                                       int* __restrict__ rowptr) {
  int b = blockIdx.x;
  int idx = b * 256 + threadIdx.x;
  if (idx == 0) rowptr[0] = 0;
  if (idx < N_NODES) {
    int off = (b == 0) ? 0 : bsum[b - 1];
    rowptr[idx + 1] = tmp[idx] + off;
  }
}

__global__ void scatter_edges(const int* __restrict__ ei, const int* __restrict__ rowptr,
                              int* __restrict__ fill, int* __restrict__ colsrc) {
  int e = blockIdx.x * blockDim.x + threadIdx.x;
  if (e >= NET) return;
  int s, d;
  if (e < NE) { s = ei[e]; d = ei[NE + e]; }
  else        { s = e - NE; d = s; }
  int pos = atomicAdd(&fill[d], 1);
  colsrc[rowptr[d] + pos] = s;
}

// ---------------- setup: weight transposes ----------------

template<int K, int NCOL>
__global__ void transpose_w(const float* __restrict__ W, ushort_t* __restrict__ Wt) {
  int idx = blockIdx.x * blockDim.x + threadIdx.x;
  if (idx >= K * NCOL) return;
  int k = idx / NCOL, n = idx - k * NCOL;
  Wt[(size_t)n * K + k] = f2bf(W[idx]);
}

// ---------------- MFMA bf16 GEMM with fused AL-logit epilogue ----------------
// C = A @ Bt^T (row-major bf16 out). A is fp32 (layer1, converted in staging) or bf16.
// AL_MODE 1: NCOL=256; each wave-column owns one full head -> direct als/ald store.
// AL_MODE 2: NCOL=128; two wave-columns -> 2-way atomicAdd (commutative = deterministic).

#define BKS 64
#define LDT 72

__device__ __forceinline__ us8 stage8(const ushort_t* p) { return *(const us8*)p; }
__device__ __forceinline__ us8 stage8(const float* p) {
  float4 f0 = *(const float4*)p;
  float4 f1 = *(const float4*)(p + 4);
  us8 o;
  o[0] = f2bf(f0.x); o[1] = f2bf(f0.y); o[2] = f2bf(f0.z); o[3] = f2bf(f0.w);
  o[4] = f2bf(f1.x); o[5] = f2bf(f1.y); o[6] = f2bf(f1.z); o[7] = f2bf(f1.w);
  return o;
}

template<int K, int NCOL, int AL_MODE, typename AT>
__global__ __launch_bounds__(256) void gemm_mfma(const AT* __restrict__ A,
                                                 const ushort_t* __restrict__ Bt,
                                                 ushort_t* __restrict__ C,
                                                 const float* __restrict__ a_s,
                                                 const float* __restrict__ a_d,
                                                 float* __restrict__ als,
                                                 float* __restrict__ ald) {
  __shared__ __align__(16) char smem[2 * 128 * LDT * 2];
  ushort_t (*Asl)[LDT] = (ushort_t(*)[LDT])smem;
  ushort_t (*Bsl)[LDT] = (ushort_t(*)[LDT])(smem + 128 * LDT * 2);
  ushort_t (*Ep)[136]  = (ushort_t(*)[136])smem;

  const int tid = threadIdx.x;
  const int lane = tid & 63;
  const int wave = tid >> 6;
  const int wr = wave >> 1, wc = wave & 1;
  const int row0 = blockIdx.y * 128;
  const int col0 = blockIdx.x * 128;
  const int l15 = lane & 15, l4 = lane >> 4;

  f32x4 acc[4][4] = {};

  for (int k0 = 0; k0 < K; k0 += BKS) {
#pragma unroll
    for (int i = 0; i < 4; ++i) {
      int seg = tid + i * 256;
      int row = seg >> 3, kq = (seg & 7) * 8;
      int arow = row0 + row;
      us8 v = {0, 0, 0, 0, 0, 0, 0, 0};
      if (arow < N_NODES) v = stage8(&A[(size_t)arow * K + k0 + kq]);
      *(us8*)&Asl[row][kq] = v;
    }
#pragma unroll
    for (int i = 0; i < 4; ++i) {
      int seg = tid + i * 256;
      int row = seg >> 3, kq = (seg & 7) * 8;
      us8 v = *(const us8*)&Bt[(size_t)(col0 + row) * K + k0 + kq];
      *(us8*)&Bsl[row][kq] = v;
    }
    __syncthreads();
#pragma unroll
    for (int kk = 0; kk < BKS; kk += 32) {
      bf16x8 af[4], bfr[4];
#pragma unroll
      for (int mi = 0; mi < 4; ++mi)
        af[mi] = *(const bf16x8*)&Asl[wr * 64 + mi * 16 + l15][kk + l4 * 8];
#pragma unroll
      for (int ni = 0; ni < 4; ++ni)
        bfr[ni] = *(const bf16x8*)&Bsl[wc * 64 + ni * 16 + l15][kk + l4 * 8];
#pragma unroll
      for (int mi = 0; mi < 4; ++mi)
#pragma unroll
        for (int ni = 0; ni < 4; ++ni)
          acc[mi][ni] = __builtin_amdgcn_mfma_f32_16x16x32_bf16(af[mi], bfr[ni], acc[mi][ni], 0, 0, 0);
    }
    __syncthreads();
  }

  // ---- fused attention-logit dots: row-sum of acc * a_vec over this wave's 64 cols ----
  {
    const int albase = (AL_MODE == 1 ? col0 : 0) + wc * 64;
    float asv[4], adv[4];
#pragma unroll
    for (int ni = 0; ni < 4; ++ni) {
      asv[ni] = a_s[albase + ni * 16 + l15];
      adv[ni] = a_d[albase + ni * 16 + l15];
    }
#pragma unroll
    for (int mi = 0; mi < 4; ++mi) {
      float ps[4], pd[4];
#pragma unroll
      for (int r = 0; r < 4; ++r) {
        ps[r] = acc[mi][0][r] * asv[0] + acc[mi][1][r] * asv[1] +
                acc[mi][2][r] * asv[2] + acc[mi][3][r] * asv[3];
        pd[r] = acc[mi][0][r] * adv[0] + acc[mi][1][r] * adv[1] +
                acc[mi][2][r] * adv[2] + acc[mi][3][r] * adv[3];
      }
#pragma unroll
      for (int m = 1; m < 16; m <<= 1) {
#pragma unroll
        for (int r = 0; r < 4; ++r) {
          ps[r] += __shfl_xor(ps[r], m, 64);
          pd[r] += __shfl_xor(pd[r], m, 64);
        }
      }
      if (l15 == 0) {
#pragma unroll
        for (int r = 0; r < 4; ++r) {
          int row = row0 + wr * 64 + mi * 16 + l4 * 4 + r;
          if (row < N_NODES) {
            if (AL_MODE == 1) {
              int h = albase >> 6;
              als[row * 4 + h] = ps[r];
              ald[row * 4 + h] = pd[r];
            } else {
              atomicAdd(&als[row], ps[r]);
              atomicAdd(&ald[row], pd[r]);
            }
          }
        }
      }
    }
  }

  // ---- C epilogue: acc -> LDS (bf16) -> coalesced global ----
#pragma unroll
  for (int mi = 0; mi < 4; ++mi)
#pragma unroll
    for (int ni = 0; ni < 4; ++ni)
#pragma unroll
      for (int r = 0; r < 4; ++r)
        Ep[wr * 64 + mi * 16 + l4 * 4 + r][wc * 64 + ni * 16 + l15] = f2bf(acc[mi][ni][r]);
  __syncthreads();
  {
    int row = tid >> 1, half = tid & 1;
    int grow = row0 + row;
    if (grow < N_NODES) {
#pragma unroll
      for (int i = 0; i < 8; ++i)
        *(us8*)&C[(size_t)grow * NCOL + col0 + half * 64 + i * 8] =
            *(const us8*)&Ep[row][half * 64 + i * 8];
    }
  }
}

// ---------------- fused scores+norm: per-node exp + denominator ----------------
// Node-parallel over CSR; writes P (interleaved [NET][4] for layer1) and sinv.

__global__ __launch_bounds__(256) void sumexp1(const int* __restrict__ rowptr,
                                               const int* __restrict__ colsrc,
                                               const float* __restrict__ als,
                                               const float* __restrict__ ald,
                                               float* __restrict__ P,
                                               float* __restrict__ sinv) {
  int wave = threadIdx.x >> 6, lane = threadIdx.x & 63;
  int n = blockIdx.x * 4 + wave;
  if (n >= N_NODES) return;
  float4 ad = *(const float4*)&ald[n * 4];
  int beg = rowptr[n], end = rowptr[n + 1];
  float s0 = 0.f, s1 = 0.f, s2 = 0.f, s3 = 0.f;
  for (int i = beg + lane; i < end; i += 64) {
    int src = colsrc[i];
    float4 as = *(const float4*)&als[src * 4];
    float sc; float4 p;
    sc = as.x + ad.x; sc = sc > 0.f ? sc : NEG_SLOPE * sc; p.x = __expf(sc);
    sc = as.y + ad.y; sc = sc > 0.f ? sc : NEG_SLOPE * sc; p.y = __expf(sc);
    sc = as.z + ad.z; sc = sc > 0.f ? sc : NEG_SLOPE * sc; p.z = __expf(sc);
    sc = as.w + ad.w; sc = sc > 0.f ? sc : NEG_SLOPE * sc; p.w = __expf(sc);
    *(float4*)&P[(size_t)i * 4] = p;
    s0 += p.x; s1 += p.y; s2 += p.z; s3 += p.w;
  }
#pragma unroll
  for (int off = 32; off; off >>= 1) {
    s0 += __shfl_down(s0, off, 64);
    s1 += __shfl_down(s1, off, 64);
    s2 += __shfl_down(s2, off, 64);
    s3 += __shfl_down(s3, off, 64);
  }
  if (lane == 0) {
    float4 r = make_float4(1.f / s0, 1.f / s1, 1.f / s2, 1.f / s3);
    *(float4*)&sinv[n * 4] = r;
  }
}

__global__ __launch_bounds__(256) void sumexp2(const int* __restrict__ rowptr,
                                               const int* __restrict__ colsrc,
                                               const float* __restrict__ als,
                                               const float* __restrict__ ald,
                                               float* __restrict__ P,
                                               float* __restrict__ sinv) {
  int wave = threadIdx.x >> 6, lane = threadIdx.x & 63;
  int n = blockIdx.x * 4 + wave;
  if (n >= N_NODES) return;
  float ad = ald[n];
  int beg = rowptr[n], end = rowptr[n + 1];
  float s = 0.f;
  for (int i = beg + lane; i < end; i += 64) {
    float sc = als[colsrc[i]] + ad;
    sc = sc > 0.f ? sc : NEG_SLOPE * sc;
    float p = __expf(sc);
    P[i] = p;
    s += p;
  }
#pragma unroll
  for (int off = 32; off; off >>= 1) s += __shfl_down(s, off, 64);
  if (lane == 0) sinv[n] = 1.f / s;
}

// ---------------- weighted gather aggregation ----------------
// layer1: wave per node; 2 edges in flight (half-waves); lane covers 8 ch via 16B load.

__global__ __launch_bounds__(256) void agg1(const int* __restrict__ rowptr,
                                            const int* __restrict__ colsrc,
                                            const ushort_t* __restrict__ Hb,
                                            const float* __restrict__ P,
                                            const float* __restrict__ sinv,
                                            const float* __restrict__ b1,
                                            ushort_t* __restrict__ X2b) {
  int wave = threadIdx.x >> 6, lane = threadIdx.x & 63;
  int n = blockIdx.x * 4 + wave;
  if (n >= N_NODES) return;
  int half = lane >> 5, li = lane & 31, h = li >> 3;
  int beg = rowptr[n], end = rowptr[n + 1];
  float a[8] = {};
  for (int i = beg + half; i < end; i += 2) {
    int src = colsrc[i];
    float w = P[(size_t)i * 4 + h];
    uint4 v = *(const uint4*)&Hb[(size_t)src * C1 + li * 8];
    a[0] = fmaf(w, u2f_lo(v.x), a[0]); a[1] = fmaf(w, u2f_hi(v.x), a[1]);
    a[2] = fmaf(w, u2f_lo(v.y), a[2]); a[3] = fmaf(w, u2f_hi(v.y), a[3]);
    a[4] = fmaf(w, u2f_lo(v.z), a[4]); a[5] = fmaf(w, u2f_hi(v.z), a[5]);
    a[6] = fmaf(w, u2f_lo(v.w), a[6]); a[7] = fmaf(w, u2f_hi(v.w), a[7]);
  }
#pragma unroll
  for (int j = 0; j < 8; ++j) a[j] += __shfl_xor(a[j], 32, 64);
  if (lane < 32) {
    float si = sinv[n * 4 + h];
    int c = li * 8;
    float4 bb0 = *(const float4*)&b1[c];
    float4 bb1 = *(const float4*)&b1[c + 4];
    ushort_t o[8];
    o[0] = f2bf(fmaxf(a[0] * si + bb0.x, 0.f));
    o[1] = f2bf(fmaxf(a[1] * si + bb0.y, 0.f));
    o[2] = f2bf(fmaxf(a[2] * si + bb0.z, 0.f));
    o[3] = f2bf(fmaxf(a[3] * si + bb0.w, 0.f));
    o[4] = f2bf(fmaxf(a[4] * si + bb1.x, 0.f));
    o[5] = f2bf(fmaxf(a[5] * si + bb1.y, 0.f));
    o[6] = f2bf(fmaxf(a[6] * si + bb1.z, 0.f));
    o[7] = f2bf(fmaxf(a[7] * si + bb1.w, 0.f));
    *(us8*)&X2b[(size_t)n * C1 + c] = *(const us8*)o;
  }
}

// layer2: wave per node; 4 edges in flight (quarter-waves); 16 lanes x 8 ch = 128.
__global__ __launch_bounds__(256) void agg2(const int* __restrict__ rowptr,
                                            const int* __restrict__ colsrc,
                                            const ushort_t* __restrict__ Hb,
                                            const float* __restrict__ P,
                                            const float* __restrict__ sinv,
                                            const float* __restrict__ b2,
                                            float* __restrict__ out) {
  int wave = threadIdx.x >> 6, lane = threadIdx.x & 63;
  int n = blockIdx.x * 4 + wave;
  if (n >= N_NODES) return;
  int quarter = lane >> 4, li = lane & 15;
  int beg = rowptr[n], end = rowptr[n + 1];
  float a[8] = {};
  for (int i = beg + quarter; i < end; i += 4) {
    int src = colsrc[i];
    float w = P[i];
    uint4 v = *(const uint4*)&Hb[(size_t)src * F_OUT + li * 8];
    a[0] = fmaf(w, u2f_lo(v.x), a[0]); a[1] = fmaf(w, u2f_hi(v.x), a[1]);
    a[2] = fmaf(w, u2f_lo(v.y), a[2]); a[3] = fmaf(w, u2f_hi(v.y), a[3]);
    a[4] = fmaf(w, u2f_lo(v.z), a[4]); a[5] = fmaf(w, u2f_hi(v.z), a[5]);
    a[6] = fmaf(w, u2f_lo(v.w), a[6]); a[7] = fmaf(w, u2f_hi(v.w), a[7]);
  }
#pragma unroll
  for (int j = 0; j < 8; ++j) a[j] += __shfl_xor(a[j], 16, 64);
#pragma unroll
  for (int j = 0; j < 8; ++j) a[j] += __shfl_xor(a[j], 32, 64);
  if (lane < 16) {
    float si = sinv[n];
    int c = li * 8;
    float4 bb0 = *(const float4*)&b2[c];
    float4 bb1 = *(const float4*)&b2[c + 4];
    float4 o0, o1;
    o0.x = a[0] * si + bb0.x; o0.y = a[1] * si + bb0.y;
    o0.z = a[2] * si + bb0.z; o0.w = a[3] * si + bb0.w;
    o1.x = a[4] * si + bb1.x; o1.y = a[5] * si + bb1.y;
    o1.z = a[6] * si + bb1.z; o1.w = a[7] * si + bb1.w;
    *(float4*)&out[(size_t)n * F_OUT + c] = o0;
    *(float4*)&out[(size_t)n * F_OUT + c + 4] = o1;
  }
}

// ---------------- launch ----------------

extern "C" void kernel_launch(void* const* d_in, const int* in_sizes, int n_in,
                              void* d_out, int out_size, void* d_ws, size_t ws_size,
                              hipStream_t stream) {
  const float* X   = (const float*)d_in[0];
  const int*   EI  = (const int*)d_in[1];
  const float* W1  = (const float*)d_in[2];
  const float* a1s = (const float*)d_in[3];
  const float* a1d = (const float*)d_in[4];
  const float* b1  = (const float*)d_in[5];
  const float* W2  = (const float*)d_in[6];
  const float* a2s = (const float*)d_in[7];
  const float* a2d = (const float*)d_in[8];
  const float* b2  = (const float*)d_in[9];
  float* out = (float*)d_out;

  char* ws = (char*)d_ws;
  size_t off = 0;
  auto alloc = [&](size_t bytes) -> void* {
    void* p = ws + off;
    off += (bytes + 255) & ~(size_t)255;
    return p;
  };
  int* deg        = (int*)alloc((size_t)N_NODES * 4);
  int* fill       = (int*)alloc((size_t)N_NODES * 4);
  int* rowptr     = (int*)alloc((size_t)(N_NODES + 1) * 4);
  int* scantmp    = (int*)alloc((size_t)N_NODES * 4);
  int* bsum       = (int*)alloc((size_t)SCAN_NBLKS * 4);
  int* colsrc     = (int*)alloc((size_t)NET * 4);
  ushort_t* W1t   = (ushort_t*)alloc((size_t)C1 * F_IN * 2);
  ushort_t* W2t   = (ushort_t*)alloc((size_t)F_OUT * C1 * 2);
  ushort_t* H1b   = (ushort_t*)alloc((size_t)N_NODES * C1 * 2);   // 25.6MB, reused as H2b
  float* ALS1     = (float*)alloc((size_t)N_NODES * HEADS * 4);
  float* ALD1     = (float*)alloc((size_t)N_NODES * HEADS * 4);
  float* SINV1    = (float*)alloc((size_t)N_NODES * HEADS * 4);
  float* P1       = (float*)alloc((size_t)NET * HEADS * 4);       // interleaved [NET][4]
  ushort_t* X2b   = (ushort_t*)alloc((size_t)N_NODES * C1 * 2);   // bf16 (gemm2 A)
  float* ALS2     = (float*)alloc((size_t)N_NODES * 4);
  float* ALD2     = (float*)alloc((size_t)N_NODES * 4);
  float* SINV2    = (float*)alloc((size_t)N_NODES * 4);
  float* P2       = (float*)alloc((size_t)NET * 4);
  ushort_t* H2b = H1b;  // H1b dead after agg1

  hipMemsetAsync(deg, 0, (size_t)N_NODES * 4, stream);
  hipMemsetAsync(fill, 0, (size_t)N_NODES * 4, stream);
  hipMemsetAsync(ALS2, 0, (size_t)N_NODES * 4, stream);   // 2-way atomic accumulators
  hipMemsetAsync(ALD2, 0, (size_t)N_NODES * 4, stream);

  // CSR build
  count_deg<<<(NET + 255) / 256, 256, 0, stream>>>(EI, deg);
  scan_blocks<<<SCAN_NBLKS, 256, 0, stream>>>(deg, scantmp, bsum);
  scan_bsum<<<1, 256, 0, stream>>>(bsum);
  finalize_rowptr<<<SCAN_NBLKS, 256, 0, stream>>>(scantmp, bsum, rowptr);
  scatter_edges<<<(NET + 255) / 256, 256, 0, stream>>>(EI, rowptr, fill, colsrc);

  // weight transposes (bf16)
  transpose_w<F_IN, C1><<<(F_IN * C1 + 255) / 256, 256, 0, stream>>>(W1, W1t);
  transpose_w<C1, F_OUT><<<(C1 * F_OUT + 255) / 256, 256, 0, stream>>>(W2, W2t);

  // layer 1 (A = fp32 X, converted during LDS staging)
  {
    dim3 grid(C1 / 128, (N_NODES + 127) / 128);
    gemm_mfma<F_IN, C1, 1, float><<<grid, 256, 0, stream>>>(X, W1t, H1b, a1s, a1d, ALS1, ALD1);
  }
  sumexp1<<<(N_NODES + 3) / 4, 256, 0, stream>>>(rowptr, colsrc, ALS1, ALD1, P1, SINV1);
  agg1<<<(N_NODES + 3) / 4, 256, 0, stream>>>(rowptr, colsrc, H1b, P1, SINV1, b1, X2b);

  // layer 2
  {
    dim3 grid(F_OUT / 128, (N_NODES + 127) / 128);
    gemm_mfma<C1, F_OUT, 2, ushort_t><<<grid, 256, 0, stream>>>(X2b, W2t, H2b, a2s, a2d, ALS2, ALD2);
  }
  sumexp2<<<(N_NODES + 3) / 4, 256, 0, stream>>>(rowptr, colsrc, ALS2, ALD2, P2, SINV2);
  agg2<<<(N_NODES + 3) / 4, 256, 0, stream>>>(rowptr, colsrc, H2b, P2, SINV2, b2, out);
}

// Round 8
// 250.834 us; speedup vs baseline: 1.7410x; 1.1347x over previous
//
#include <hip/hip_runtime.h>
#include <math.h>

#define N_NODES 50000
#define F_IN    128
#define HIDC    64
#define HEADS   4
#define C1      (HEADS*HIDC)   // 256
#define F_OUT   128
#define NE      800000
#define NET     (NE + N_NODES) // 850000 edges incl self-loops
#define NEG_SLOPE 0.2f
#define SCAN_NBLKS ((N_NODES + 255) / 256)   // 196

typedef unsigned short ushort_t;
typedef __attribute__((ext_vector_type(8))) short bf16x8;
typedef __attribute__((ext_vector_type(8))) unsigned short us8;
typedef __attribute__((ext_vector_type(4))) float f32x4;

__device__ __forceinline__ float b2f(ushort_t x) {
  return __uint_as_float(((unsigned int)x) << 16);
}
__device__ __forceinline__ ushort_t f2bf(float f) {  // RNE, no NaN expected
  unsigned int u = __float_as_uint(f);
  return (ushort_t)((u + 0x7fffu + ((u >> 16) & 1u)) >> 16);
}
__device__ __forceinline__ float u2f_lo(unsigned int u) { return __uint_as_float(u << 16); }
__device__ __forceinline__ float u2f_hi(unsigned int u) { return __uint_as_float(u & 0xffff0000u); }

// ---------------- CSR build ----------------

__global__ void count_deg(const int* __restrict__ ei, int* __restrict__ deg) {
  int e = blockIdx.x * blockDim.x + threadIdx.x;
  if (e >= NET) return;
  int d = (e < NE) ? ei[NE + e] : (e - NE);
  atomicAdd(&deg[d], 1);
}

__global__ __launch_bounds__(256) void scan_blocks(const int* __restrict__ deg,
                                                   int* __restrict__ tmp,
                                                   int* __restrict__ bsum) {
  __shared__ int sh[256];
  int b = blockIdx.x, t = threadIdx.x;
  int idx = b * 256 + t;
  sh[t] = (idx < N_NODES) ? deg[idx] : 0;
  __syncthreads();
#pragma unroll
  for (int off = 1; off < 256; off <<= 1) {
    int u = (t >= off) ? sh[t - off] : 0;
    __syncthreads();
    sh[t] += u;
    __syncthreads();
  }
  if (idx < N_NODES) tmp[idx] = sh[t];
  if (t == 255) bsum[b] = sh[255];
}

__global__ __launch_bounds__(256) void scan_bsum(int* __restrict__ bsum) {
  __shared__ int sh[256];
  int t = threadIdx.x;
  sh[t] = (t < SCAN_NBLKS) ? bsum[t] : 0;
  __syncthreads();
#pragma unroll
  for (int off = 1; off < 256; off <<= 1) {
    int u = (t >= off) ? sh[t - off] : 0;
    __syncthreads();
    sh[t] += u;
    __syncthreads();
  }
  if (t < SCAN_NBLKS) bsum[t] = sh[t];
}

__global__ __launch_bounds__(256) void finalize_rowptr(const int* __restrict__ tmp,
                                                       const int* __restrict__ bsum,
                                                       int* __restrict__ rowptr) {
  int b = blockIdx.x;
  int idx = b * 256 + threadIdx.x;
  if (idx == 0) rowptr[0] = 0;
  if (idx < N_NODES) {
    int off = (b == 0) ? 0 : bsum[b - 1];
    rowptr[idx + 1] = tmp[idx] + off;
  }
}

__global__ void scatter_edges(const int* __restrict__ ei, const int* __restrict__ rowptr,
                              int* __restrict__ fill, int* __restrict__ colsrc) {
  int e = blockIdx.x * blockDim.x + threadIdx.x;
  if (e >= NET) return;
  int s, d;
  if (e < NE) { s = ei[e]; d = ei[NE + e]; }
  else        { s = e - NE; d = s; }
  int pos = atomicAdd(&fill[d], 1);
  colsrc[rowptr[d] + pos] = s;
}

// ---------------- setup: weight transposes ----------------

template<int K, int NCOL>
__global__ void transpose_w(const float* __restrict__ W, ushort_t* __restrict__ Wt) {
  int idx = blockIdx.x * blockDim.x + threadIdx.x;
  if (idx >= K * NCOL) return;
  int k = idx / NCOL, n = idx - k * NCOL;
  Wt[(size_t)n * K + k] = f2bf(W[idx]);
}

// ---------------- MFMA bf16 GEMM with fused AL-logit epilogue ----------------

#define BKS 64
#define LDT 72

__device__ __forceinline__ us8 stage8(const ushort_t* p) { return *(const us8*)p; }
__device__ __forceinline__ us8 stage8(const float* p) {
  float4 f0 = *(const float4*)p;
  float4 f1 = *(const float4*)(p + 4);
  us8 o;
  o[0] = f2bf(f0.x); o[1] = f2bf(f0.y); o[2] = f2bf(f0.z); o[3] = f2bf(f0.w);
  o[4] = f2bf(f1.x); o[5] = f2bf(f1.y); o[6] = f2bf(f1.z); o[7] = f2bf(f1.w);
  return o;
}

template<int K, int NCOL, int AL_MODE, typename AT>
__global__ __launch_bounds__(256) void gemm_mfma(const AT* __restrict__ A,
                                                 const ushort_t* __restrict__ Bt,
                                                 ushort_t* __restrict__ C,
                                                 const float* __restrict__ a_s,
                                                 const float* __restrict__ a_d,
                                                 float* __restrict__ als,
                                                 float* __restrict__ ald) {
  __shared__ __align__(16) char smem[2 * 128 * LDT * 2];
  ushort_t (*Asl)[LDT] = (ushort_t(*)[LDT])smem;
  ushort_t (*Bsl)[LDT] = (ushort_t(*)[LDT])(smem + 128 * LDT * 2);
  ushort_t (*Ep)[136]  = (ushort_t(*)[136])smem;

  const int tid = threadIdx.x;
  const int lane = tid & 63;
  const int wave = tid >> 6;
  const int wr = wave >> 1, wc = wave & 1;
  const int row0 = blockIdx.y * 128;
  const int col0 = blockIdx.x * 128;
  const int l15 = lane & 15, l4 = lane >> 4;

  f32x4 acc[4][4] = {};

  for (int k0 = 0; k0 < K; k0 += BKS) {
#pragma unroll
    for (int i = 0; i < 4; ++i) {
      int seg = tid + i * 256;
      int row = seg >> 3, kq = (seg & 7) * 8;
      int arow = row0 + row;
      us8 v = {0, 0, 0, 0, 0, 0, 0, 0};
      if (arow < N_NODES) v = stage8(&A[(size_t)arow * K + k0 + kq]);
      *(us8*)&Asl[row][kq] = v;
    }
#pragma unroll
    for (int i = 0; i < 4; ++i) {
      int seg = tid + i * 256;
      int row = seg >> 3, kq = (seg & 7) * 8;
      us8 v = *(const us8*)&Bt[(size_t)(col0 + row) * K + k0 + kq];
      *(us8*)&Bsl[row][kq] = v;
    }
    __syncthreads();
#pragma unroll
    for (int kk = 0; kk < BKS; kk += 32) {
      bf16x8 af[4], bfr[4];
#pragma unroll
      for (int mi = 0; mi < 4; ++mi)
        af[mi] = *(const bf16x8*)&Asl[wr * 64 + mi * 16 + l15][kk + l4 * 8];
#pragma unroll
      for (int ni = 0; ni < 4; ++ni)
        bfr[ni] = *(const bf16x8*)&Bsl[wc * 64 + ni * 16 + l15][kk + l4 * 8];
#pragma unroll
      for (int mi = 0; mi < 4; ++mi)
#pragma unroll
        for (int ni = 0; ni < 4; ++ni)
          acc[mi][ni] = __builtin_amdgcn_mfma_f32_16x16x32_bf16(af[mi], bfr[ni], acc[mi][ni], 0, 0, 0);
    }
    __syncthreads();
  }

  // ---- fused attention-logit dots ----
  {
    const int albase = (AL_MODE == 1 ? col0 : 0) + wc * 64;
    float asv[4], adv[4];
#pragma unroll
    for (int ni = 0; ni < 4; ++ni) {
      asv[ni] = a_s[albase + ni * 16 + l15];
      adv[ni] = a_d[albase + ni * 16 + l15];
    }
#pragma unroll
    for (int mi = 0; mi < 4; ++mi) {
      float ps[4], pd[4];
#pragma unroll
      for (int r = 0; r < 4; ++r) {
        ps[r] = acc[mi][0][r] * asv[0] + acc[mi][1][r] * asv[1] +
                acc[mi][2][r] * asv[2] + acc[mi][3][r] * asv[3];
        pd[r] = acc[mi][0][r] * adv[0] + acc[mi][1][r] * adv[1] +
                acc[mi][2][r] * adv[2] + acc[mi][3][r] * adv[3];
      }
#pragma unroll
      for (int m = 1; m < 16; m <<= 1) {
#pragma unroll
        for (int r = 0; r < 4; ++r) {
          ps[r] += __shfl_xor(ps[r], m, 64);
          pd[r] += __shfl_xor(pd[r], m, 64);
        }
      }
      if (l15 == 0) {
#pragma unroll
        for (int r = 0; r < 4; ++r) {
          int row = row0 + wr * 64 + mi * 16 + l4 * 4 + r;
          if (row < N_NODES) {
            if (AL_MODE == 1) {
              int h = albase >> 6;
              als[row * 4 + h] = ps[r];
              ald[row * 4 + h] = pd[r];
            } else {
              atomicAdd(&als[row], ps[r]);
              atomicAdd(&ald[row], pd[r]);
            }
          }
        }
      }
    }
  }

  // ---- C epilogue: acc -> LDS (bf16) -> coalesced global ----
#pragma unroll
  for (int mi = 0; mi < 4; ++mi)
#pragma unroll
    for (int ni = 0; ni < 4; ++ni)
#pragma unroll
      for (int r = 0; r < 4; ++r)
        Ep[wr * 64 + mi * 16 + l4 * 4 + r][wc * 64 + ni * 16 + l15] = f2bf(acc[mi][ni][r]);
  __syncthreads();
  {
    int row = tid >> 1, half = tid & 1;
    int grow = row0 + row;
    if (grow < N_NODES) {
#pragma unroll
      for (int i = 0; i < 8; ++i)
        *(us8*)&C[(size_t)grow * NCOL + col0 + half * 64 + i * 8] =
            *(const us8*)&Ep[row][half * 64 + i * 8];
    }
  }
}

// ---------------- fused softmax + gather aggregation ----------------
// w = exp(leakyrelu(als[src]+ald[n])) computed inline; acc += w*H[src]; s += w;
// out = acc/s + b. No P/sinv buffers, no separate sumexp pass.

// layer1: wave per node; half-wave (32 lanes x 16B = 512B row) per edge; unroll 2.
__global__ __launch_bounds__(256) void agg1(const int* __restrict__ rowptr,
                                            const int* __restrict__ colsrc,
                                            const ushort_t* __restrict__ Hb,
                                            const float* __restrict__ als,
                                            const float* __restrict__ ald,
                                            const float* __restrict__ b1,
                                            ushort_t* __restrict__ X2b) {
  int wave = threadIdx.x >> 6, lane = threadIdx.x & 63;
  int n = blockIdx.x * 4 + wave;
  if (n >= N_NODES) return;
  int half = lane >> 5, li = lane & 31, h = li >> 3;
  float ad = ald[n * 4 + h];
  int beg = rowptr[n], end = rowptr[n + 1];
  float a[8] = {};
  float s = 0.f;
  int i = beg + half;
  for (; i + 2 < end; i += 4) {
    int s0 = colsrc[i], s1 = colsrc[i + 2];
    float sc0 = als[s0 * 4 + h] + ad;
    float sc1 = als[s1 * 4 + h] + ad;
    uint4 v0 = *(const uint4*)&Hb[(size_t)s0 * C1 + li * 8];
    uint4 v1 = *(const uint4*)&Hb[(size_t)s1 * C1 + li * 8];
    sc0 = sc0 > 0.f ? sc0 : NEG_SLOPE * sc0;
    sc1 = sc1 > 0.f ? sc1 : NEG_SLOPE * sc1;
    float w0 = __expf(sc0), w1 = __expf(sc1);
    s += w0 + w1;
    a[0] = fmaf(w0, u2f_lo(v0.x), a[0]); a[1] = fmaf(w0, u2f_hi(v0.x), a[1]);
    a[2] = fmaf(w0, u2f_lo(v0.y), a[2]); a[3] = fmaf(w0, u2f_hi(v0.y), a[3]);
    a[4] = fmaf(w0, u2f_lo(v0.z), a[4]); a[5] = fmaf(w0, u2f_hi(v0.z), a[5]);
    a[6] = fmaf(w0, u2f_lo(v0.w), a[6]); a[7] = fmaf(w0, u2f_hi(v0.w), a[7]);
    a[0] = fmaf(w1, u2f_lo(v1.x), a[0]); a[1] = fmaf(w1, u2f_hi(v1.x), a[1]);
    a[2] = fmaf(w1, u2f_lo(v1.y), a[2]); a[3] = fmaf(w1, u2f_hi(v1.y), a[3]);
    a[4] = fmaf(w1, u2f_lo(v1.z), a[4]); a[5] = fmaf(w1, u2f_hi(v1.z), a[5]);
    a[6] = fmaf(w1, u2f_lo(v1.w), a[6]); a[7] = fmaf(w1, u2f_hi(v1.w), a[7]);
  }
  for (; i < end; i += 2) {
    int s0 = colsrc[i];
    float sc0 = als[s0 * 4 + h] + ad;
    uint4 v0 = *(const uint4*)&Hb[(size_t)s0 * C1 + li * 8];
    sc0 = sc0 > 0.f ? sc0 : NEG_SLOPE * sc0;
    float w0 = __expf(sc0);
    s += w0;
    a[0] = fmaf(w0, u2f_lo(v0.x), a[0]); a[1] = fmaf(w0, u2f_hi(v0.x), a[1]);
    a[2] = fmaf(w0, u2f_lo(v0.y), a[2]); a[3] = fmaf(w0, u2f_hi(v0.y), a[3]);
    a[4] = fmaf(w0, u2f_lo(v0.z), a[4]); a[5] = fmaf(w0, u2f_hi(v0.z), a[5]);
    a[6] = fmaf(w0, u2f_lo(v0.w), a[6]); a[7] = fmaf(w0, u2f_hi(v0.w), a[7]);
  }
#pragma unroll
  for (int j = 0; j < 8; ++j) a[j] += __shfl_xor(a[j], 32, 64);
  s += __shfl_xor(s, 32, 64);
  if (lane < 32) {
    float si = 1.f / s;
    int c = li * 8;
    float4 bb0 = *(const float4*)&b1[c];
    float4 bb1 = *(const float4*)&b1[c + 4];
    ushort_t o[8];
    o[0] = f2bf(fmaxf(a[0] * si + bb0.x, 0.f));
    o[1] = f2bf(fmaxf(a[1] * si + bb0.y, 0.f));
    o[2] = f2bf(fmaxf(a[2] * si + bb0.z, 0.f));
    o[3] = f2bf(fmaxf(a[3] * si + bb0.w, 0.f));
    o[4] = f2bf(fmaxf(a[4] * si + bb1.x, 0.f));
    o[5] = f2bf(fmaxf(a[5] * si + bb1.y, 0.f));
    o[6] = f2bf(fmaxf(a[6] * si + bb1.z, 0.f));
    o[7] = f2bf(fmaxf(a[7] * si + bb1.w, 0.f));
    *(us8*)&X2b[(size_t)n * C1 + c] = *(const us8*)o;
  }
}

// layer2: wave per node; quarter-wave (16 lanes x 16B = 256B row) per edge; unroll 2.
__global__ __launch_bounds__(256) void agg2(const int* __restrict__ rowptr,
                                            const int* __restrict__ colsrc,
                                            const ushort_t* __restrict__ Hb,
                                            const float* __restrict__ als,
                                            const float* __restrict__ ald,
                                            const float* __restrict__ b2,
                                            float* __restrict__ out) {
  int wave = threadIdx.x >> 6, lane = threadIdx.x & 63;
  int n = blockIdx.x * 4 + wave;
  if (n >= N_NODES) return;
  int quarter = lane >> 4, li = lane & 15;
  float ad = ald[n];
  int beg = rowptr[n], end = rowptr[n + 1];
  float a[8] = {};
  float s = 0.f;
  int i = beg + quarter;
  for (; i + 4 < end; i += 8) {
    int s0 = colsrc[i], s1 = colsrc[i + 4];
    float sc0 = als[s0] + ad;
    float sc1 = als[s1] + ad;
    uint4 v0 = *(const uint4*)&Hb[(size_t)s0 * F_OUT + li * 8];
    uint4 v1 = *(const uint4*)&Hb[(size_t)s1 * F_OUT + li * 8];
    sc0 = sc0 > 0.f ? sc0 : NEG_SLOPE * sc0;
    sc1 = sc1 > 0.f ? sc1 : NEG_SLOPE * sc1;
    float w0 = __expf(sc0), w1 = __expf(sc1);
    s += w0 + w1;
    a[0] = fmaf(w0, u2f_lo(v0.x), a[0]); a[1] = fmaf(w0, u2f_hi(v0.x), a[1]);
    a[2] = fmaf(w0, u2f_lo(v0.y), a[2]); a[3] = fmaf(w0, u2f_hi(v0.y), a[3]);
    a[4] = fmaf(w0, u2f_lo(v0.z), a[4]); a[5] = fmaf(w0, u2f_hi(v0.z), a[5]);
    a[6] = fmaf(w0, u2f_lo(v0.w), a[6]); a[7] = fmaf(w0, u2f_hi(v0.w), a[7]);
    a[0] = fmaf(w1, u2f_lo(v1.x), a[0]); a[1] = fmaf(w1, u2f_hi(v1.x), a[1]);
    a[2] = fmaf(w1, u2f_lo(v1.y), a[2]); a[3] = fmaf(w1, u2f_hi(v1.y), a[3]);
    a[4] = fmaf(w1, u2f_lo(v1.z), a[4]); a[5] = fmaf(w1, u2f_hi(v1.z), a[5]);
    a[6] = fmaf(w1, u2f_lo(v1.w), a[6]); a[7] = fmaf(w1, u2f_hi(v1.w), a[7]);
  }
  for (; i < end; i += 4) {
    int s0 = colsrc[i];
    float sc0 = als[s0] + ad;
    uint4 v0 = *(const uint4*)&Hb[(size_t)s0 * F_OUT + li * 8];
    sc0 = sc0 > 0.f ? sc0 : NEG_SLOPE * sc0;
    float w0 = __expf(sc0);
    s += w0;
    a[0] = fmaf(w0, u2f_lo(v0.x), a[0]); a[1] = fmaf(w0, u2f_hi(v0.x), a[1]);
    a[2] = fmaf(w0, u2f_lo(v0.y), a[2]); a[3] = fmaf(w0, u2f_hi(v0.y), a[3]);
    a[4] = fmaf(w0, u2f_lo(v0.z), a[4]); a[5] = fmaf(w0, u2f_hi(v0.z), a[5]);
    a[6] = fmaf(w0, u2f_lo(v0.w), a[6]); a[7] = fmaf(w0, u2f_hi(v0.w), a[7]);
  }
#pragma unroll
  for (int j = 0; j < 8; ++j) a[j] += __shfl_xor(a[j], 16, 64);
#pragma unroll
  for (int j = 0; j < 8; ++j) a[j] += __shfl_xor(a[j], 32, 64);
  s += __shfl_xor(s, 16, 64);
  s += __shfl_xor(s, 32, 64);
  if (lane < 16) {
    float si = 1.f / s;
    int c = li * 8;
    float4 bb0 = *(const float4*)&b2[c];
    float4 bb1 = *(const float4*)&b2[c + 4];
    float4 o0, o1;
    o0.x = a[0] * si + bb0.x; o0.y = a[1] * si + bb0.y;
    o0.z = a[2] * si + bb0.z; o0.w = a[3] * si + bb0.w;
    o1.x = a[4] * si + bb1.x; o1.y = a[5] * si + bb1.y;
    o1.z = a[6] * si + bb1.z; o1.w = a[7] * si + bb1.w;
    *(float4*)&out[(size_t)n * F_OUT + c] = o0;
    *(float4*)&out[(size_t)n * F_OUT + c + 4] = o1;
  }
}

// ---------------- launch ----------------

extern "C" void kernel_launch(void* const* d_in, const int* in_sizes, int n_in,
                              void* d_out, int out_size, void* d_ws, size_t ws_size,
                              hipStream_t stream) {
  const float* X   = (const float*)d_in[0];
  const int*   EI  = (const int*)d_in[1];
  const float* W1  = (const float*)d_in[2];
  const float* a1s = (const float*)d_in[3];
  const float* a1d = (const float*)d_in[4];
  const float* b1  = (const float*)d_in[5];
  const float* W2  = (const float*)d_in[6];
  const float* a2s = (const float*)d_in[7];
  const float* a2d = (const float*)d_in[8];
  const float* b2  = (const float*)d_in[9];
  float* out = (float*)d_out;

  char* ws = (char*)d_ws;
  size_t off = 0;
  auto alloc = [&](size_t bytes) -> void* {
    void* p = ws + off;
    off += (bytes + 255) & ~(size_t)255;
    return p;
  };
  int* deg        = (int*)alloc((size_t)N_NODES * 4);
  int* fill       = (int*)alloc((size_t)N_NODES * 4);
  int* rowptr     = (int*)alloc((size_t)(N_NODES + 1) * 4);
  int* scantmp    = (int*)alloc((size_t)N_NODES * 4);
  int* bsum       = (int*)alloc((size_t)SCAN_NBLKS * 4);
  int* colsrc     = (int*)alloc((size_t)NET * 4);
  ushort_t* W1t   = (ushort_t*)alloc((size_t)C1 * F_IN * 2);
  ushort_t* W2t   = (ushort_t*)alloc((size_t)F_OUT * C1 * 2);
  ushort_t* H1b   = (ushort_t*)alloc((size_t)N_NODES * C1 * 2);   // reused as H2b
  float* ALS1     = (float*)alloc((size_t)N_NODES * HEADS * 4);
  float* ALD1     = (float*)alloc((size_t)N_NODES * HEADS * 4);
  ushort_t* X2b   = (ushort_t*)alloc((size_t)N_NODES * C1 * 2);
  float* ALS2     = (float*)alloc((size_t)N_NODES * 4);
  float* ALD2     = (float*)alloc((size_t)N_NODES * 4);
  ushort_t* H2b = H1b;  // H1b dead after agg1

  hipMemsetAsync(deg, 0, (size_t)N_NODES * 4, stream);
  hipMemsetAsync(fill, 0, (size_t)N_NODES * 4, stream);
  hipMemsetAsync(ALS2, 0, (size_t)N_NODES * 4, stream);   // 2-way atomic accumulators
  hipMemsetAsync(ALD2, 0, (size_t)N_NODES * 4, stream);

  // CSR build
  count_deg<<<(NET + 255) / 256, 256, 0, stream>>>(EI, deg);
  scan_blocks<<<SCAN_NBLKS, 256, 0, stream>>>(deg, scantmp, bsum);
  scan_bsum<<<1, 256, 0, stream>>>(bsum);
  finalize_rowptr<<<SCAN_NBLKS, 256, 0, stream>>>(scantmp, bsum, rowptr);
  scatter_edges<<<(NET + 255) / 256, 256, 0, stream>>>(EI, rowptr, fill, colsrc);

  // weight transposes (bf16)
  transpose_w<F_IN, C1><<<(F_IN * C1 + 255) / 256, 256, 0, stream>>>(W1, W1t);
  transpose_w<C1, F_OUT><<<(C1 * F_OUT + 255) / 256, 256, 0, stream>>>(W2, W2t);

  // layer 1 (A = fp32 X, converted during LDS staging)
  {
    dim3 grid(C1 / 128, (N_NODES + 127) / 128);
    gemm_mfma<F_IN, C1, 1, float><<<grid, 256, 0, stream>>>(X, W1t, H1b, a1s, a1d, ALS1, ALD1);
  }
  agg1<<<(N_NODES + 3) / 4, 256, 0, stream>>>(rowptr, colsrc, H1b, ALS1, ALD1, b1, X2b);

  // layer 2
  {
    dim3 grid(F_OUT / 128, (N_NODES + 127) / 128);
    gemm_mfma<C1, F_OUT, 2, ushort_t><<<grid, 256, 0, stream>>>(X2b, W2t, H2b, a2s, a2d, ALS2, ALD2);
  }
  agg2<<<(N_NODES + 3) / 4, 256, 0, stream>>>(rowptr, colsrc, H2b, ALS2, ALD2, b2, out);
}

// Round 10
// 248.973 us; speedup vs baseline: 1.7540x; 1.0075x over previous
//
#include <hip/hip_runtime.h>
#include <math.h>

#define N_NODES 50000
#define F_IN    128
#define HIDC    64
#define HEADS   4
#define C1      (HEADS*HIDC)   // 256
#define F_OUT   128
#define NE      800000
#define NET     (NE + N_NODES) // 850000 edges incl self-loops
#define NEG_SLOPE 0.2f
#define SCAN_NBLKS ((N_NODES + 255) / 256)   // 196

typedef unsigned short ushort_t;
typedef __attribute__((ext_vector_type(8))) short bf16x8;
typedef __attribute__((ext_vector_type(8))) unsigned short us8;
typedef __attribute__((ext_vector_type(4))) float f32x4;

__device__ __forceinline__ float b2f(ushort_t x) {
  return __uint_as_float(((unsigned int)x) << 16);
}
__device__ __forceinline__ ushort_t f2bf(float f) {  // RNE, no NaN expected
  unsigned int u = __float_as_uint(f);
  return (ushort_t)((u + 0x7fffu + ((u >> 16) & 1u)) >> 16);
}
__device__ __forceinline__ float u2f_lo(unsigned int u) { return __uint_as_float(u << 16); }
__device__ __forceinline__ float u2f_hi(unsigned int u) { return __uint_as_float(u & 0xffff0000u); }

// accumulate 8 bf16 channels (packed in uint4) scaled by weight ww into a[8]
__device__ __forceinline__ void fma8(float ww, uint4 vv, float* a) {
  a[0] = fmaf(ww, u2f_lo(vv.x), a[0]); a[1] = fmaf(ww, u2f_hi(vv.x), a[1]);
  a[2] = fmaf(ww, u2f_lo(vv.y), a[2]); a[3] = fmaf(ww, u2f_hi(vv.y), a[3]);
  a[4] = fmaf(ww, u2f_lo(vv.z), a[4]); a[5] = fmaf(ww, u2f_hi(vv.z), a[5]);
  a[6] = fmaf(ww, u2f_lo(vv.w), a[6]); a[7] = fmaf(ww, u2f_hi(vv.w), a[7]);
}

// ---------------- CSR build ----------------

__global__ void count_deg(const int* __restrict__ ei, int* __restrict__ deg) {
  int e = blockIdx.x * blockDim.x + threadIdx.x;
  if (e >= NET) return;
  int d = (e < NE) ? ei[NE + e] : (e - NE);
  atomicAdd(&deg[d], 1);
}

__global__ __launch_bounds__(256) void scan_blocks(const int* __restrict__ deg,
                                                   int* __restrict__ tmp,
                                                   int* __restrict__ bsum) {
  __shared__ int sh[256];
  int b = blockIdx.x, t = threadIdx.x;
  int idx = b * 256 + t;
  sh[t] = (idx < N_NODES) ? deg[idx] : 0;
  __syncthreads();
#pragma unroll
  for (int off = 1; off < 256; off <<= 1) {
    int u = (t >= off) ? sh[t - off] : 0;
    __syncthreads();
    sh[t] += u;
    __syncthreads();
  }
  if (idx < N_NODES) tmp[idx] = sh[t];
  if (t == 255) bsum[b] = sh[255];
}

__global__ __launch_bounds__(256) void scan_bsum(int* __restrict__ bsum) {
  __shared__ int sh[256];
  int t = threadIdx.x;
  sh[t] = (t < SCAN_NBLKS) ? bsum[t] : 0;
  __syncthreads();
#pragma unroll
  for (int off = 1; off < 256; off <<= 1) {
    int u = (t >= off) ? sh[t - off] : 0;
    __syncthreads();
    sh[t] += u;
    __syncthreads();
  }
  if (t < SCAN_NBLKS) bsum[t] = sh[t];
}

__global__ __launch_bounds__(256) void finalize_rowptr(const int* __restrict__ tmp,
                                                       const int* __restrict__ bsum,
                                                       int* __restrict__ rowptr) {
  int b = blockIdx.x;
  int idx = b * 256 + threadIdx.x;
  if (idx == 0) rowptr[0] = 0;
  if (idx < N_NODES) {
    int off = (b == 0) ? 0 : bsum[b - 1];
    rowptr[idx + 1] = tmp[idx] + off;
  }
}

__global__ void scatter_edges(const int* __restrict__ ei, const int* __restrict__ rowptr,
                              int* __restrict__ fill, int* __restrict__ colsrc) {
  int e = blockIdx.x * blockDim.x + threadIdx.x;
  if (e >= NET) return;
  int s, d;
  if (e < NE) { s = ei[e]; d = ei[NE + e]; }
  else        { s = e - NE; d = s; }
  int pos = atomicAdd(&fill[d], 1);
  colsrc[rowptr[d] + pos] = s;
}

// ---------------- setup: weight transposes ----------------

template<int K, int NCOL>
__global__ void transpose_w(const float* __restrict__ W, ushort_t* __restrict__ Wt) {
  int idx = blockIdx.x * blockDim.x + threadIdx.x;
  if (idx >= K * NCOL) return;
  int k = idx / NCOL, n = idx - k * NCOL;
  Wt[(size_t)n * K + k] = f2bf(W[idx]);
}

// ---------------- MFMA bf16 GEMM with fused AL-logit epilogue ----------------

#define BKS 64
#define LDT 72

__device__ __forceinline__ us8 stage8(const ushort_t* p) { return *(const us8*)p; }
__device__ __forceinline__ us8 stage8(const float* p) {
  float4 f0 = *(const float4*)p;
  float4 f1 = *(const float4*)(p + 4);
  us8 o;
  o[0] = f2bf(f0.x); o[1] = f2bf(f0.y); o[2] = f2bf(f0.z); o[3] = f2bf(f0.w);
  o[4] = f2bf(f1.x); o[5] = f2bf(f1.y); o[6] = f2bf(f1.z); o[7] = f2bf(f1.w);
  return o;
}

template<int K, int NCOL, int AL_MODE, typename AT>
__global__ __launch_bounds__(256) void gemm_mfma(const AT* __restrict__ A,
                                                 const ushort_t* __restrict__ Bt,
                                                 ushort_t* __restrict__ C,
                                                 const float* __restrict__ a_s,
                                                 const float* __restrict__ a_d,
                                                 float* __restrict__ als,
                                                 float* __restrict__ ald) {
  __shared__ __align__(16) char smem[2 * 128 * LDT * 2];
  ushort_t (*Asl)[LDT] = (ushort_t(*)[LDT])smem;
  ushort_t (*Bsl)[LDT] = (ushort_t(*)[LDT])(smem + 128 * LDT * 2);
  ushort_t (*Ep)[136]  = (ushort_t(*)[136])smem;

  const int tid = threadIdx.x;
  const int lane = tid & 63;
  const int wave = tid >> 6;
  const int wr = wave >> 1, wc = wave & 1;
  const int row0 = blockIdx.y * 128;
  const int col0 = blockIdx.x * 128;
  const int l15 = lane & 15, l4 = lane >> 4;

  f32x4 acc[4][4] = {};

  for (int k0 = 0; k0 < K; k0 += BKS) {
#pragma unroll
    for (int i = 0; i < 4; ++i) {
      int seg = tid + i * 256;
      int row = seg >> 3, kq = (seg & 7) * 8;
      int arow = row0 + row;
      us8 v = {0, 0, 0, 0, 0, 0, 0, 0};
      if (arow < N_NODES) v = stage8(&A[(size_t)arow * K + k0 + kq]);
      *(us8*)&Asl[row][kq] = v;
    }
#pragma unroll
    for (int i = 0; i < 4; ++i) {
      int seg = tid + i * 256;
      int row = seg >> 3, kq = (seg & 7) * 8;
      us8 v = *(const us8*)&Bt[(size_t)(col0 + row) * K + k0 + kq];
      *(us8*)&Bsl[row][kq] = v;
    }
    __syncthreads();
#pragma unroll
    for (int kk = 0; kk < BKS; kk += 32) {
      bf16x8 af[4], bfr[4];
#pragma unroll
      for (int mi = 0; mi < 4; ++mi)
        af[mi] = *(const bf16x8*)&Asl[wr * 64 + mi * 16 + l15][kk + l4 * 8];
#pragma unroll
      for (int ni = 0; ni < 4; ++ni)
        bfr[ni] = *(const bf16x8*)&Bsl[wc * 64 + ni * 16 + l15][kk + l4 * 8];
#pragma unroll
      for (int mi = 0; mi < 4; ++mi)
#pragma unroll
        for (int ni = 0; ni < 4; ++ni)
          acc[mi][ni] = __builtin_amdgcn_mfma_f32_16x16x32_bf16(af[mi], bfr[ni], acc[mi][ni], 0, 0, 0);
    }
    __syncthreads();
  }

  // ---- fused attention-logit dots ----
  {
    const int albase = (AL_MODE == 1 ? col0 : 0) + wc * 64;
    float asv[4], adv[4];
#pragma unroll
    for (int ni = 0; ni < 4; ++ni) {
      asv[ni] = a_s[albase + ni * 16 + l15];
      adv[ni] = a_d[albase + ni * 16 + l15];
    }
#pragma unroll
    for (int mi = 0; mi < 4; ++mi) {
      float ps[4], pd[4];
#pragma unroll
      for (int r = 0; r < 4; ++r) {
        ps[r] = acc[mi][0][r] * asv[0] + acc[mi][1][r] * asv[1] +
                acc[mi][2][r] * asv[2] + acc[mi][3][r] * asv[3];
        pd[r] = acc[mi][0][r] * adv[0] + acc[mi][1][r] * adv[1] +
                acc[mi][2][r] * adv[2] + acc[mi][3][r] * adv[3];
      }
#pragma unroll
      for (int m = 1; m < 16; m <<= 1) {
#pragma unroll
        for (int r = 0; r < 4; ++r) {
          ps[r] += __shfl_xor(ps[r], m, 64);
          pd[r] += __shfl_xor(pd[r], m, 64);
        }
      }
      if (l15 == 0) {
#pragma unroll
        for (int r = 0; r < 4; ++r) {
          int row = row0 + wr * 64 + mi * 16 + l4 * 4 + r;
          if (row < N_NODES) {
            if (AL_MODE == 1) {
              int h = albase >> 6;
              als[row * 4 + h] = ps[r];
              ald[row * 4 + h] = pd[r];
            } else {
              atomicAdd(&als[row], ps[r]);
              atomicAdd(&ald[row], pd[r]);
            }
          }
        }
      }
    }
  }

  // ---- C epilogue: acc -> LDS (bf16) -> coalesced global ----
#pragma unroll
  for (int mi = 0; mi < 4; ++mi)
#pragma unroll
    for (int ni = 0; ni < 4; ++ni)
#pragma unroll
      for (int r = 0; r < 4; ++r)
        Ep[wr * 64 + mi * 16 + l4 * 4 + r][wc * 64 + ni * 16 + l15] = f2bf(acc[mi][ni][r]);
  __syncthreads();
  {
    int row = tid >> 1, half = tid & 1;
    int grow = row0 + row;
    if (grow < N_NODES) {
#pragma unroll
      for (int i = 0; i < 8; ++i)
        *(us8*)&C[(size_t)grow * NCOL + col0 + half * 64 + i * 8] =
            *(const us8*)&Ep[row][half * 64 + i * 8];
    }
  }
}

// ---------------- fused softmax + gather aggregation ----------------
// w = exp(leakyrelu(als[src]+ald[n])) inline; acc += w*H[src]; s += w; out = acc/s + b.

// layer1: wave per node; half-wave (32 lanes x 16B = 512B row) per edge; 4 edges in flight/half.
__global__ __launch_bounds__(256) void agg1(const int* __restrict__ rowptr,
                                            const int* __restrict__ colsrc,
                                            const ushort_t* __restrict__ Hb,
                                            const float* __restrict__ als,
                                            const float* __restrict__ ald,
                                            const float* __restrict__ b1,
                                            ushort_t* __restrict__ X2b) {
  int wave = threadIdx.x >> 6, lane = threadIdx.x & 63;
  int n = blockIdx.x * 4 + wave;
  if (n >= N_NODES) return;
  int half = lane >> 5, li = lane & 31, h = li >> 3;
  float ad = ald[n * 4 + h];
  int beg = rowptr[n], end = rowptr[n + 1];
  float a[8] = {};
  float s = 0.f;
  int i = beg + half;
  for (; i + 6 < end; i += 8) {
    int s0 = colsrc[i], s1 = colsrc[i + 2], s2 = colsrc[i + 4], s3 = colsrc[i + 6];
    float sc0 = als[s0 * 4 + h] + ad;
    float sc1 = als[s1 * 4 + h] + ad;
    float sc2 = als[s2 * 4 + h] + ad;
    float sc3 = als[s3 * 4 + h] + ad;
    uint4 v0 = *(const uint4*)&Hb[(size_t)s0 * C1 + li * 8];
    uint4 v1 = *(const uint4*)&Hb[(size_t)s1 * C1 + li * 8];
    uint4 v2 = *(const uint4*)&Hb[(size_t)s2 * C1 + li * 8];
    uint4 v3 = *(const uint4*)&Hb[(size_t)s3 * C1 + li * 8];
    sc0 = sc0 > 0.f ? sc0 : NEG_SLOPE * sc0;
    sc1 = sc1 > 0.f ? sc1 : NEG_SLOPE * sc1;
    sc2 = sc2 > 0.f ? sc2 : NEG_SLOPE * sc2;
    sc3 = sc3 > 0.f ? sc3 : NEG_SLOPE * sc3;
    float w0 = __expf(sc0), w1 = __expf(sc1), w2 = __expf(sc2), w3 = __expf(sc3);
    s += (w0 + w1) + (w2 + w3);
    fma8(w0, v0, a); fma8(w1, v1, a); fma8(w2, v2, a); fma8(w3, v3, a);
  }
  for (; i + 2 < end; i += 4) {
    int s0 = colsrc[i], s1 = colsrc[i + 2];
    float sc0 = als[s0 * 4 + h] + ad;
    float sc1 = als[s1 * 4 + h] + ad;
    uint4 v0 = *(const uint4*)&Hb[(size_t)s0 * C1 + li * 8];
    uint4 v1 = *(const uint4*)&Hb[(size_t)s1 * C1 + li * 8];
    sc0 = sc0 > 0.f ? sc0 : NEG_SLOPE * sc0;
    sc1 = sc1 > 0.f ? sc1 : NEG_SLOPE * sc1;
    float w0 = __expf(sc0), w1 = __expf(sc1);
    s += w0 + w1;
    fma8(w0, v0, a); fma8(w1, v1, a);
  }
  for (; i < end; i += 2) {
    int s0 = colsrc[i];
    float sc0 = als[s0 * 4 + h] + ad;
    uint4 v0 = *(const uint4*)&Hb[(size_t)s0 * C1 + li * 8];
    sc0 = sc0 > 0.f ? sc0 : NEG_SLOPE * sc0;
    float w0 = __expf(sc0);
    s += w0;
    fma8(w0, v0, a);
  }
#pragma unroll
  for (int j = 0; j < 8; ++j) a[j] += __shfl_xor(a[j], 32, 64);
  s += __shfl_xor(s, 32, 64);
  if (lane < 32) {
    float si = 1.f / s;
    int c = li * 8;
    float4 bb0 = *(const float4*)&b1[c];
    float4 bb1 = *(const float4*)&b1[c + 4];
    ushort_t o[8];
    o[0] = f2bf(fmaxf(a[0] * si + bb0.x, 0.f));
    o[1] = f2bf(fmaxf(a[1] * si + bb0.y, 0.f));
    o[2] = f2bf(fmaxf(a[2] * si + bb0.z, 0.f));
    o[3] = f2bf(fmaxf(a[3] * si + bb0.w, 0.f));
    o[4] = f2bf(fmaxf(a[4] * si + bb1.x, 0.f));
    o[5] = f2bf(fmaxf(a[5] * si + bb1.y, 0.f));
    o[6] = f2bf(fmaxf(a[6] * si + bb1.z, 0.f));
    o[7] = f2bf(fmaxf(a[7] * si + bb1.w, 0.f));
    *(us8*)&X2b[(size_t)n * C1 + c] = *(const us8*)o;
  }
}

// layer2: wave per node; quarter-wave (16 lanes x 16B = 256B row) per edge; 4 in flight/quarter.
__global__ __launch_bounds__(256) void agg2(const int* __restrict__ rowptr,
                                            const int* __restrict__ colsrc,
                                            const ushort_t* __restrict__ Hb,
                                            const float* __restrict__ als,
                                            const float* __restrict__ ald,
                                            const float* __restrict__ b2,
                                            float* __restrict__ out) {
  int wave = threadIdx.x >> 6, lane = threadIdx.x & 63;
  int n = blockIdx.x * 4 + wave;
  if (n >= N_NODES) return;
  int quarter = lane >> 4, li = lane & 15;
  float ad = ald[n];
  int beg = rowptr[n], end = rowptr[n + 1];
  float a[8] = {};
  float s = 0.f;
  int i = beg + quarter;
  for (; i + 12 < end; i += 16) {
    int s0 = colsrc[i], s1 = colsrc[i + 4], s2 = colsrc[i + 8], s3 = colsrc[i + 12];
    float sc0 = als[s0] + ad;
    float sc1 = als[s1] + ad;
    float sc2 = als[s2] + ad;
    float sc3 = als[s3] + ad;
    uint4 v0 = *(const uint4*)&Hb[(size_t)s0 * F_OUT + li * 8];
    uint4 v1 = *(const uint4*)&Hb[(size_t)s1 * F_OUT + li * 8];
    uint4 v2 = *(const uint4*)&Hb[(size_t)s2 * F_OUT + li * 8];
    uint4 v3 = *(const uint4*)&Hb[(size_t)s3 * F_OUT + li * 8];
    sc0 = sc0 > 0.f ? sc0 : NEG_SLOPE * sc0;
    sc1 = sc1 > 0.f ? sc1 : NEG_SLOPE * sc1;
    sc2 = sc2 > 0.f ? sc2 : NEG_SLOPE * sc2;
    sc3 = sc3 > 0.f ? sc3 : NEG_SLOPE * sc3;
    float w0 = __expf(sc0), w1 = __expf(sc1), w2 = __expf(sc2), w3 = __expf(sc3);
    s += (w0 + w1) + (w2 + w3);
    fma8(w0, v0, a); fma8(w1, v1, a); fma8(w2, v2, a); fma8(w3, v3, a);
  }
  for (; i + 4 < end; i += 8) {
    int s0 = colsrc[i], s1 = colsrc[i + 4];
    float sc0 = als[s0] + ad;
    float sc1 = als[s1] + ad;
    uint4 v0 = *(const uint4*)&Hb[(size_t)s0 * F_OUT + li * 8];
    uint4 v1 = *(const uint4*)&Hb[(size_t)s1 * F_OUT + li * 8];
    sc0 = sc0 > 0.f ? sc0 : NEG_SLOPE * sc0;
    sc1 = sc1 > 0.f ? sc1 : NEG_SLOPE * sc1;
    float w0 = __expf(sc0), w1 = __expf(sc1);
    s += w0 + w1;
    fma8(w0, v0, a); fma8(w1, v1, a);
  }
  for (; i < end; i += 4) {
    int s0 = colsrc[i];
    float sc0 = als[s0] + ad;
    uint4 v0 = *(const uint4*)&Hb[(size_t)s0 * F_OUT + li * 8];
    sc0 = sc0 > 0.f ? sc0 : NEG_SLOPE * sc0;
    float w0 = __expf(sc0);
    s += w0;
    fma8(w0, v0, a);
  }
#pragma unroll
  for (int j = 0; j < 8; ++j) a[j] += __shfl_xor(a[j], 16, 64);
#pragma unroll
  for (int j = 0; j < 8; ++j) a[j] += __shfl_xor(a[j], 32, 64);
  s += __shfl_xor(s, 16, 64);
  s += __shfl_xor(s, 32, 64);
  if (lane < 16) {
    float si = 1.f / s;
    int c = li * 8;
    float4 bb0 = *(const float4*)&b2[c];
    float4 bb1 = *(const float4*)&b2[c + 4];
    float4 o0, o1;
    o0.x = a[0] * si + bb0.x; o0.y = a[1] * si + bb0.y;
    o0.z = a[2] * si + bb0.z; o0.w = a[3] * si + bb0.w;
    o1.x = a[4] * si + bb1.x; o1.y = a[5] * si + bb1.y;
    o1.z = a[6] * si + bb1.z; o1.w = a[7] * si + bb1.w;
    *(float4*)&out[(size_t)n * F_OUT + c] = o0;
    *(float4*)&out[(size_t)n * F_OUT + c + 4] = o1;
  }
}

// ---------------- launch ----------------

extern "C" void kernel_launch(void* const* d_in, const int* in_sizes, int n_in,
                              void* d_out, int out_size, void* d_ws, size_t ws_size,
                              hipStream_t stream) {
  const float* X   = (const float*)d_in[0];
  const int*   EI  = (const int*)d_in[1];
  const float* W1  = (const float*)d_in[2];
  const float* a1s = (const float*)d_in[3];
  const float* a1d = (const float*)d_in[4];
  const float* b1  = (const float*)d_in[5];
  const float* W2  = (const float*)d_in[6];
  const float* a2s = (const float*)d_in[7];
  const float* a2d = (const float*)d_in[8];
  const float* b2  = (const float*)d_in[9];
  float* out = (float*)d_out;

  char* ws = (char*)d_ws;
  size_t off = 0;
  auto alloc = [&](size_t bytes) -> void* {
    void* p = ws + off;
    off += (bytes + 255) & ~(size_t)255;
    return p;
  };
  int* deg        = (int*)alloc((size_t)N_NODES * 4);
  int* fill       = (int*)alloc((size_t)N_NODES * 4);
  int* rowptr     = (int*)alloc((size_t)(N_NODES + 1) * 4);
  int* scantmp    = (int*)alloc((size_t)N_NODES * 4);
  int* bsum       = (int*)alloc((size_t)SCAN_NBLKS * 4);
  int* colsrc     = (int*)alloc((size_t)NET * 4);
  ushort_t* W1t   = (ushort_t*)alloc((size_t)C1 * F_IN * 2);
  ushort_t* W2t   = (ushort_t*)alloc((size_t)F_OUT * C1 * 2);
  ushort_t* H1b   = (ushort_t*)alloc((size_t)N_NODES * C1 * 2);   // reused as H2b
  float* ALS1     = (float*)alloc((size_t)N_NODES * HEADS * 4);
  float* ALD1     = (float*)alloc((size_t)N_NODES * HEADS * 4);
  ushort_t* X2b   = (ushort_t*)alloc((size_t)N_NODES * C1 * 2);
  float* ALS2     = (float*)alloc((size_t)N_NODES * 4);
  float* ALD2     = (float*)alloc((size_t)N_NODES * 4);
  ushort_t* H2b = H1b;  // H1b dead after agg1

  hipMemsetAsync(deg, 0, (size_t)N_NODES * 4, stream);
  hipMemsetAsync(fill, 0, (size_t)N_NODES * 4, stream);
  hipMemsetAsync(ALS2, 0, (size_t)N_NODES * 4, stream);   // 2-way atomic accumulators
  hipMemsetAsync(ALD2, 0, (size_t)N_NODES * 4, stream);

  // CSR build
  count_deg<<<(NET + 255) / 256, 256, 0, stream>>>(EI, deg);
  scan_blocks<<<SCAN_NBLKS, 256, 0, stream>>>(deg, scantmp, bsum);
  scan_bsum<<<1, 256, 0, stream>>>(bsum);
  finalize_rowptr<<<SCAN_NBLKS, 256, 0, stream>>>(scantmp, bsum, rowptr);
  scatter_edges<<<(NET + 255) / 256, 256, 0, stream>>>(EI, rowptr, fill, colsrc);

  // weight transposes (bf16)
  transpose_w<F_IN, C1><<<(F_IN * C1 + 255) / 256, 256, 0, stream>>>(W1, W1t);
  transpose_w<C1, F_OUT><<<(C1 * F_OUT + 255) / 256, 256, 0, stream>>>(W2, W2t);

  // layer 1 (A = fp32 X, converted during LDS staging)
  {
    dim3 grid(C1 / 128, (N_NODES + 127) / 128);
    gemm_mfma<F_IN, C1, 1, float><<<grid, 256, 0, stream>>>(X, W1t, H1b, a1s, a1d, ALS1, ALD1);
  }
  agg1<<<(N_NODES + 3) / 4, 256, 0, stream>>>(rowptr, colsrc, H1b, ALS1, ALD1, b1, X2b);

  // layer 2
  {
    dim3 grid(F_OUT / 128, (N_NODES + 127) / 128);
    gemm_mfma<C1, F_OUT, 2, ushort_t><<<grid, 256, 0, stream>>>(X2b, W2t, H2b, a2s, a2d, ALS2, ALD2);
  }
  agg2<<<(N_NODES + 3) / 4, 256, 0, stream>>>(rowptr, colsrc, H2b, ALS2, ALD2, b2, out);
}

// Round 13
// 226.903 us; speedup vs baseline: 1.9247x; 1.0973x over previous
//
#include <hip/hip_runtime.h>
#include <math.h>

#define N_NODES 50000
#define F_IN    128
#define HIDC    64
#define HEADS   4
#define C1      (HEADS*HIDC)   // 256
#define F_OUT   128
#define NE      800000
#define NET     (NE + N_NODES) // 850000 edges incl self-loops
#define NEG_SLOPE 0.2f
#define SCAN_NBLKS ((N_NODES + 255) / 256)   // 196

typedef unsigned short ushort_t;
typedef signed char    schar_t;
typedef __attribute__((ext_vector_type(8))) short bf16x8;
typedef __attribute__((ext_vector_type(8))) unsigned short us8;
typedef __attribute__((ext_vector_type(4))) float f32x4;

__device__ __forceinline__ float b2f(ushort_t x) {
  return __uint_as_float(((unsigned int)x) << 16);
}
__device__ __forceinline__ ushort_t f2bf(float f) {  // RNE, no NaN expected
  unsigned int u = __float_as_uint(f);
  return (ushort_t)((u + 0x7fffu + ((u >> 16) & 1u)) >> 16);
}
__device__ __forceinline__ float u2f_lo(unsigned int u) { return __uint_as_float(u << 16); }
__device__ __forceinline__ float u2f_hi(unsigned int u) { return __uint_as_float(u & 0xffff0000u); }

__device__ __forceinline__ void fma8v(float ww, uint4 vv, float* a) {  // bf16 x8
  a[0] = fmaf(ww, u2f_lo(vv.x), a[0]); a[1] = fmaf(ww, u2f_hi(vv.x), a[1]);
  a[2] = fmaf(ww, u2f_lo(vv.y), a[2]); a[3] = fmaf(ww, u2f_hi(vv.y), a[3]);
  a[4] = fmaf(ww, u2f_lo(vv.z), a[4]); a[5] = fmaf(ww, u2f_hi(vv.z), a[5]);
  a[6] = fmaf(ww, u2f_lo(vv.w), a[6]); a[7] = fmaf(ww, u2f_hi(vv.w), a[7]);
}
// int8 x8 decode: wsc = w * scale already folded; denominator uses raw w.
__device__ __forceinline__ void fma8q(float wsc, uint2 vv, float* a) {
  int x = (int)vv.x, y = (int)vv.y;
  a[0] = fmaf(wsc, (float)(schar_t)(x),        a[0]);
  a[1] = fmaf(wsc, (float)(schar_t)(x >> 8),   a[1]);
  a[2] = fmaf(wsc, (float)(schar_t)(x >> 16),  a[2]);
  a[3] = fmaf(wsc, (float)(x >> 24),           a[3]);
  a[4] = fmaf(wsc, (float)(schar_t)(y),        a[4]);
  a[5] = fmaf(wsc, (float)(schar_t)(y >> 8),   a[5]);
  a[6] = fmaf(wsc, (float)(schar_t)(y >> 16),  a[6]);
  a[7] = fmaf(wsc, (float)(y >> 24),           a[7]);
}

// ---------------- CSR build ----------------

__global__ void count_deg(const int* __restrict__ ei, int* __restrict__ deg) {
  int e = blockIdx.x * blockDim.x + threadIdx.x;
  if (e >= NET) return;
  int d = (e < NE) ? ei[NE + e] : (e - NE);
  atomicAdd(&deg[d], 1);
}

__global__ __launch_bounds__(256) void scan_blocks(const int* __restrict__ deg,
                                                   int* __restrict__ tmp,
                                                   int* __restrict__ bsum) {
  __shared__ int sh[256];
  int b = blockIdx.x, t = threadIdx.x;
  int idx = b * 256 + t;
  sh[t] = (idx < N_NODES) ? deg[idx] : 0;
  __syncthreads();
#pragma unroll
  for (int off = 1; off < 256; off <<= 1) {
    int u = (t >= off) ? sh[t - off] : 0;
    __syncthreads();
    sh[t] += u;
    __syncthreads();
  }
  if (idx < N_NODES) tmp[idx] = sh[t];
  if (t == 255) bsum[b] = sh[255];
}

__global__ __launch_bounds__(256) void scan_bsum(int* __restrict__ bsum) {
  __shared__ int sh[256];
  int t = threadIdx.x;
  sh[t] = (t < SCAN_NBLKS) ? bsum[t] : 0;
  __syncthreads();
#pragma unroll
  for (int off = 1; off < 256; off <<= 1) {
    int u = (t >= off) ? sh[t - off] : 0;
    __syncthreads();
    sh[t] += u;
    __syncthreads();
  }
  if (t < SCAN_NBLKS) bsum[t] = sh[t];
}

__global__ __launch_bounds__(256) void finalize_rowptr(const int* __restrict__ tmp,
                                                       const int* __restrict__ bsum,
                                                       int* __restrict__ rowptr) {
  int b = blockIdx.x;
  int idx = b * 256 + threadIdx.x;
  if (idx == 0) rowptr[0] = 0;
  if (idx < N_NODES) {
    int off = (b == 0) ? 0 : bsum[b - 1];
    rowptr[idx + 1] = tmp[idx] + off;
  }
}

__global__ void scatter_edges(const int* __restrict__ ei, const int* __restrict__ rowptr,
                              int* __restrict__ fill, int* __restrict__ colsrc) {
  int e = blockIdx.x * blockDim.x + threadIdx.x;
  if (e >= NET) return;
  int s, d;
  if (e < NE) { s = ei[e]; d = ei[NE + e]; }
  else        { s = e - NE; d = s; }
  int pos = atomicAdd(&fill[d], 1);
  colsrc[rowptr[d] + pos] = s;
}

// ---------------- setup: both weight transposes in one kernel ----------------

__global__ void transpose_both(const float* __restrict__ W1, ushort_t* __restrict__ W1t,
                               const float* __restrict__ W2, ushort_t* __restrict__ W2t) {
  int idx = blockIdx.x * blockDim.x + threadIdx.x;
  if (idx < F_IN * C1) {
    int k = idx / C1, n = idx - k * C1;
    W1t[(size_t)n * F_IN + k] = f2bf(W1[idx]);
  } else {
    int j = idx - F_IN * C1;
    if (j < C1 * F_OUT) {
      int k = j / F_OUT, n = j - k * F_OUT;
      W2t[(size_t)n * C1 + k] = f2bf(W2[j]);
    }
  }
}

// ---------------- MFMA bf16 GEMM with fused AL-logit epilogue ----------------
// CT: schar_t -> int8 C + per-(node,head) scale (layer1); ushort_t -> bf16 C.

#define BKS 64
#define LDT 72

__device__ __forceinline__ us8 stage8(const ushort_t* p) { return *(const us8*)p; }
__device__ __forceinline__ us8 stage8(const float* p) {
  float4 f0 = *(const float4*)p;
  float4 f1 = *(const float4*)(p + 4);
  us8 o;
  o[0] = f2bf(f0.x); o[1] = f2bf(f0.y); o[2] = f2bf(f0.z); o[3] = f2bf(f0.w);
  o[4] = f2bf(f1.x); o[5] = f2bf(f1.y); o[6] = f2bf(f1.z); o[7] = f2bf(f1.w);
  return o;
}

template<int K, int NCOL, int AL_MODE, typename AT, typename CT>
__global__ __launch_bounds__(256) void gemm_mfma(const AT* __restrict__ A,
                                                 const ushort_t* __restrict__ Bt,
                                                 CT* __restrict__ C,
                                                 float* __restrict__ scales,
                                                 const float* __restrict__ a_s,
                                                 const float* __restrict__ a_d,
                                                 float* __restrict__ als,
                                                 float* __restrict__ ald) {
  __shared__ __align__(16) char smem[2 * 128 * LDT * 2];
  ushort_t (*Asl)[LDT] = (ushort_t(*)[LDT])smem;
  ushort_t (*Bsl)[LDT] = (ushort_t(*)[LDT])(smem + 128 * LDT * 2);

  const int tid = threadIdx.x;
  const int lane = tid & 63;
  const int wave = tid >> 6;
  const int wr = wave >> 1, wc = wave & 1;
  const int row0 = blockIdx.y * 128;
  const int col0 = blockIdx.x * 128;
  const int l15 = lane & 15, l4 = lane >> 4;

  f32x4 acc[4][4] = {};

  for (int k0 = 0; k0 < K; k0 += BKS) {
#pragma unroll
    for (int i = 0; i < 4; ++i) {
      int seg = tid + i * 256;
      int row = seg >> 3, kq = (seg & 7) * 8;
      int arow = row0 + row;
      us8 v = {0, 0, 0, 0, 0, 0, 0, 0};
      if (arow < N_NODES) v = stage8(&A[(size_t)arow * K + k0 + kq]);
      *(us8*)&Asl[row][kq] = v;
    }
#pragma unroll
    for (int i = 0; i < 4; ++i) {
      int seg = tid + i * 256;
      int row = seg >> 3, kq = (seg & 7) * 8;
      us8 v = *(const us8*)&Bt[(size_t)(col0 + row) * K + k0 + kq];
      *(us8*)&Bsl[row][kq] = v;
    }
    __syncthreads();
#pragma unroll
    for (int kk = 0; kk < BKS; kk += 32) {
      bf16x8 af[4], bfr[4];
#pragma unroll
      for (int mi = 0; mi < 4; ++mi)
        af[mi] = *(const bf16x8*)&Asl[wr * 64 + mi * 16 + l15][kk + l4 * 8];
#pragma unroll
      for (int ni = 0; ni < 4; ++ni)
        bfr[ni] = *(const bf16x8*)&Bsl[wc * 64 + ni * 16 + l15][kk + l4 * 8];
#pragma unroll
      for (int mi = 0; mi < 4; ++mi)
#pragma unroll
        for (int ni = 0; ni < 4; ++ni)
          acc[mi][ni] = __builtin_amdgcn_mfma_f32_16x16x32_bf16(af[mi], bfr[ni], acc[mi][ni], 0, 0, 0);
    }
    __syncthreads();
  }

  // ---- fused attention-logit dots ----
  {
    const int albase = (AL_MODE == 1 ? col0 : 0) + wc * 64;
    float asv[4], adv[4];
#pragma unroll
    for (int ni = 0; ni < 4; ++ni) {
      asv[ni] = a_s[albase + ni * 16 + l15];
      adv[ni] = a_d[albase + ni * 16 + l15];
    }
#pragma unroll
    for (int mi = 0; mi < 4; ++mi) {
      float ps[4], pd[4];
#pragma unroll
      for (int r = 0; r < 4; ++r) {
        ps[r] = acc[mi][0][r] * asv[0] + acc[mi][1][r] * asv[1] +
                acc[mi][2][r] * asv[2] + acc[mi][3][r] * asv[3];
        pd[r] = acc[mi][0][r] * adv[0] + acc[mi][1][r] * adv[1] +
                acc[mi][2][r] * adv[2] + acc[mi][3][r] * adv[3];
      }
#pragma unroll
      for (int m = 1; m < 16; m <<= 1) {
#pragma unroll
        for (int r = 0; r < 4; ++r) {
          ps[r] += __shfl_xor(ps[r], m, 64);
          pd[r] += __shfl_xor(pd[r], m, 64);
        }
      }
      if (l15 == 0) {
#pragma unroll
        for (int r = 0; r < 4; ++r) {
          int row = row0 + wr * 64 + mi * 16 + l4 * 4 + r;
          if (row < N_NODES) {
            if (AL_MODE == 1) {
              int h = albase >> 6;
              als[row * 4 + h] = ps[r];
              ald[row * 4 + h] = pd[r];
            } else {
              atomicAdd(&als[row], ps[r]);
              atomicAdd(&ald[row], pd[r]);
            }
          }
        }
      }
    }
  }

  // ---- C epilogue: acc -> LDS bf16 bounce -> global (int8+scale or bf16) ----
  {
    ushort_t (*Ep)[136] = (ushort_t(*)[136])smem;
#pragma unroll
    for (int mi = 0; mi < 4; ++mi)
#pragma unroll
      for (int ni = 0; ni < 4; ++ni)
#pragma unroll
        for (int r = 0; r < 4; ++r)
          Ep[wr * 64 + mi * 16 + l4 * 4 + r][wc * 64 + ni * 16 + l15] = f2bf(acc[mi][ni][r]);
    __syncthreads();
    int row = tid >> 1, half = tid & 1;
    int grow = row0 + row;
    if (grow < N_NODES) {
      if constexpr (sizeof(CT) == 1) {
        // per-thread: one (row, 64-col half) == one head's worth of channels
        float vals[64];
        float amax = 0.f;
#pragma unroll
        for (int i = 0; i < 8; ++i) {
          us8 v = *(const us8*)&Ep[row][half * 64 + i * 8];
#pragma unroll
          for (int j = 0; j < 8; ++j) {
            float f = b2f((ushort_t)v[j]);
            vals[i * 8 + j] = f;
            amax = fmaxf(amax, fabsf(f));
          }
        }
        float inv = amax > 0.f ? 127.f / amax : 0.f;
        scales[grow * 4 + (col0 >> 6) + half] = amax * (1.f / 127.f);
        schar_t ob[64];
#pragma unroll
        for (int i = 0; i < 64; ++i)
          ob[i] = (schar_t)(int)rintf(vals[i] * inv);
#pragma unroll
        for (int i = 0; i < 4; ++i)
          *(us8*)&C[(size_t)grow * NCOL + col0 + half * 64 + i * 16] =
              *(const us8*)&ob[i * 16];
      } else {
#pragma unroll
        for (int i = 0; i < 8; ++i)
          *(us8*)&C[(size_t)grow * NCOL + col0 + half * 64 + i * 8] =
              *(const us8*)&Ep[row][half * 64 + i * 8];
      }
    }
  }
}

// ---------------- fused softmax + gather aggregation ----------------

// layer1: int8 messages (8B row-slice/lane) + per-(node,head) scale; half-wave per edge,
// 4 edges in flight per half.
__global__ __launch_bounds__(256) void agg1(const int* __restrict__ rowptr,
                                            const int* __restrict__ colsrc,
                                            const schar_t* __restrict__ Hq,
                                            const float* __restrict__ Sc,
                                            const float* __restrict__ als,
                                            const float* __restrict__ ald,
                                            const float* __restrict__ b1,
                                            ushort_t* __restrict__ X2b) {
  int wave = threadIdx.x >> 6, lane = threadIdx.x & 63;
  int n = blockIdx.x * 4 + wave;
  if (n >= N_NODES) return;
  int half = lane >> 5, li = lane & 31, h = li >> 3;
  float ad = ald[n * 4 + h];
  int beg = rowptr[n], end = rowptr[n + 1];
  float a[8] = {};
  float s = 0.f;
  int i = beg + half;
  for (; i + 6 < end; i += 8) {
    int s0 = colsrc[i], s1 = colsrc[i + 2], s2 = colsrc[i + 4], s3 = colsrc[i + 6];
    float sc0 = als[s0 * 4 + h] + ad;
    float sc1 = als[s1 * 4 + h] + ad;
    float sc2 = als[s2 * 4 + h] + ad;
    float sc3 = als[s3 * 4 + h] + ad;
    float q0 = Sc[s0 * 4 + h], q1 = Sc[s1 * 4 + h], q2 = Sc[s2 * 4 + h], q3 = Sc[s3 * 4 + h];
    uint2 v0 = *(const uint2*)&Hq[(size_t)s0 * C1 + li * 8];
    uint2 v1 = *(const uint2*)&Hq[(size_t)s1 * C1 + li * 8];
    uint2 v2 = *(const uint2*)&Hq[(size_t)s2 * C1 + li * 8];
    uint2 v3 = *(const uint2*)&Hq[(size_t)s3 * C1 + li * 8];
    sc0 = sc0 > 0.f ? sc0 : NEG_SLOPE * sc0;
    sc1 = sc1 > 0.f ? sc1 : NEG_SLOPE * sc1;
    sc2 = sc2 > 0.f ? sc2 : NEG_SLOPE * sc2;
    sc3 = sc3 > 0.f ? sc3 : NEG_SLOPE * sc3;
    float w0 = __expf(sc0), w1 = __expf(sc1), w2 = __expf(sc2), w3 = __expf(sc3);
    s += (w0 + w1) + (w2 + w3);
    fma8q(w0 * q0, v0, a); fma8q(w1 * q1, v1, a);
    fma8q(w2 * q2, v2, a); fma8q(w3 * q3, v3, a);
  }
  for (; i + 2 < end; i += 4) {
    int s0 = colsrc[i], s1 = colsrc[i + 2];
    float sc0 = als[s0 * 4 + h] + ad;
    float sc1 = als[s1 * 4 + h] + ad;
    float q0 = Sc[s0 * 4 + h], q1 = Sc[s1 * 4 + h];
    uint2 v0 = *(const uint2*)&Hq[(size_t)s0 * C1 + li * 8];
    uint2 v1 = *(const uint2*)&Hq[(size_t)s1 * C1 + li * 8];
    sc0 = sc0 > 0.f ? sc0 : NEG_SLOPE * sc0;
    sc1 = sc1 > 0.f ? sc1 : NEG_SLOPE * sc1;
    float w0 = __expf(sc0), w1 = __expf(sc1);
    s += w0 + w1;
    fma8q(w0 * q0, v0, a); fma8q(w1 * q1, v1, a);
  }
  for (; i < end; i += 2) {
    int s0 = colsrc[i];
    float sc0 = als[s0 * 4 + h] + ad;
    float q0 = Sc[s0 * 4 + h];
    uint2 v0 = *(const uint2*)&Hq[(size_t)s0 * C1 + li * 8];
    sc0 = sc0 > 0.f ? sc0 : NEG_SLOPE * sc0;
    float w0 = __expf(sc0);
    s += w0;
    fma8q(w0 * q0, v0, a);
  }
#pragma unroll
  for (int j = 0; j < 8; ++j) a[j] += __shfl_xor(a[j], 32, 64);
  s += __shfl_xor(s, 32, 64);
  if (lane < 32) {
    float si = 1.f / s;
    int c = li * 8;
    float4 bb0 = *(const float4*)&b1[c];
    float4 bb1 = *(const float4*)&b1[c + 4];
    ushort_t o[8];
    o[0] = f2bf(fmaxf(a[0] * si + bb0.x, 0.f));
    o[1] = f2bf(fmaxf(a[1] * si + bb0.y, 0.f));
    o[2] = f2bf(fmaxf(a[2] * si + bb0.z, 0.f));
    o[3] = f2bf(fmaxf(a[3] * si + bb0.w, 0.f));
    o[4] = f2bf(fmaxf(a[4] * si + bb1.x, 0.f));
    o[5] = f2bf(fmaxf(a[5] * si + bb1.y, 0.f));
    o[6] = f2bf(fmaxf(a[6] * si + bb1.z, 0.f));
    o[7] = f2bf(fmaxf(a[7] * si + bb1.w, 0.f));
    *(us8*)&X2b[(size_t)n * C1 + c] = *(const us8*)o;
  }
}

// layer2: bf16 rows; quarter-wave per edge; 4 in flight per quarter.
__global__ __launch_bounds__(256) void agg2(const int* __restrict__ rowptr,
                                            const int* __restrict__ colsrc,
                                            const ushort_t* __restrict__ Hb,
                                            const float* __restrict__ als,
                                            const float* __restrict__ ald,
                                            const float* __restrict__ b2,
                                            float* __restrict__ out) {
  int wave = threadIdx.x >> 6, lane = threadIdx.x & 63;
  int n = blockIdx.x * 4 + wave;
  if (n >= N_NODES) return;
  int quarter = lane >> 4, li = lane & 15;
  float ad = ald[n];
  int beg = rowptr[n], end = rowptr[n + 1];
  float a[8] = {};
  float s = 0.f;
  int i = beg + quarter;
  for (; i + 12 < end; i += 16) {
    int s0 = colsrc[i], s1 = colsrc[i + 4], s2 = colsrc[i + 8], s3 = colsrc[i + 12];
    float sc0 = als[s0] + ad;
    float sc1 = als[s1] + ad;
    float sc2 = als[s2] + ad;
    float sc3 = als[s3] + ad;
    uint4 v0 = *(const uint4*)&Hb[(size_t)s0 * F_OUT + li * 8];
    uint4 v1 = *(const uint4*)&Hb[(size_t)s1 * F_OUT + li * 8];
    uint4 v2 = *(const uint4*)&Hb[(size_t)s2 * F_OUT + li * 8];
    uint4 v3 = *(const uint4*)&Hb[(size_t)s3 * F_OUT + li * 8];
    sc0 = sc0 > 0.f ? sc0 : NEG_SLOPE * sc0;
    sc1 = sc1 > 0.f ? sc1 : NEG_SLOPE * sc1;
    sc2 = sc2 > 0.f ? sc2 : NEG_SLOPE * sc2;
    sc3 = sc3 > 0.f ? sc3 : NEG_SLOPE * sc3;
    float w0 = __expf(sc0), w1 = __expf(sc1), w2 = __expf(sc2), w3 = __expf(sc3);
    s += (w0 + w1) + (w2 + w3);
    fma8v(w0, v0, a); fma8v(w1, v1, a); fma8v(w2, v2, a); fma8v(w3, v3, a);
  }
  for (; i + 4 < end; i += 8) {
    int s0 = colsrc[i], s1 = colsrc[i + 4];
    float sc0 = als[s0] + ad;
    float sc1 = als[s1] + ad;
    uint4 v0 = *(const uint4*)&Hb[(size_t)s0 * F_OUT + li * 8];
    uint4 v1 = *(const uint4*)&Hb[(size_t)s1 * F_OUT + li * 8];
    sc0 = sc0 > 0.f ? sc0 : NEG_SLOPE * sc0;
    sc1 = sc1 > 0.f ? sc1 : NEG_SLOPE * sc1;
    float w0 = __expf(sc0), w1 = __expf(sc1);
    s += w0 + w1;
    fma8v(w0, v0, a); fma8v(w1, v1, a);
  }
  for (; i < end; i += 4) {
    int s0 = colsrc[i];
    float sc0 = als[s0] + ad;
    uint4 v0 = *(const uint4*)&Hb[(size_t)s0 * F_OUT + li * 8];
    sc0 = sc0 > 0.f ? sc0 : NEG_SLOPE * sc0;
    float w0 = __expf(sc0);
    s += w0;
    fma8v(w0, v0, a);
  }
#pragma unroll
  for (int j = 0; j < 8; ++j) a[j] += __shfl_xor(a[j], 16, 64);
#pragma unroll
  for (int j = 0; j < 8; ++j) a[j] += __shfl_xor(a[j], 32, 64);
  s += __shfl_xor(s, 16, 64);
  s += __shfl_xor(s, 32, 64);
  if (lane < 16) {
    float si = 1.f / s;
    int c = li * 8;
    float4 bb0 = *(const float4*)&b2[c];
    float4 bb1 = *(const float4*)&b2[c + 4];
    float4 o0, o1;
    o0.x = a[0] * si + bb0.x; o0.y = a[1] * si + bb0.y;
    o0.z = a[2] * si + bb0.z; o0.w = a[3] * si + bb0.w;
    o1.x = a[4] * si + bb1.x; o1.y = a[5] * si + bb1.y;
    o1.z = a[6] * si + bb1.z; o1.w = a[7] * si + bb1.w;
    *(float4*)&out[(size_t)n * F_OUT + c] = o0;
    *(float4*)&out[(size_t)n * F_OUT + c + 4] = o1;
  }
}

// ---------------- launch ----------------

extern "C" void kernel_launch(void* const* d_in, const int* in_sizes, int n_in,
                              void* d_out, int out_size, void* d_ws, size_t ws_size,
                              hipStream_t stream) {
  const float* X   = (const float*)d_in[0];
  const int*   EI  = (const int*)d_in[1];
  const float* W1  = (const float*)d_in[2];
  const float* a1s = (const float*)d_in[3];
  const float* a1d = (const float*)d_in[4];
  const float* b1  = (const float*)d_in[5];
  const float* W2  = (const float*)d_in[6];
  const float* a2s = (const float*)d_in[7];
  const float* a2d = (const float*)d_in[8];
  const float* b2  = (const float*)d_in[9];
  float* out = (float*)d_out;

  char* ws = (char*)d_ws;
  size_t off = 0;
  auto alloc = [&](size_t bytes) -> void* {
    void* p = ws + off;
    off += (bytes + 255) & ~(size_t)255;
    return p;
  };
  // zero-init block first (single memset covers deg..ALD2)
  int* deg        = (int*)alloc((size_t)N_NODES * 4);
  int* fill       = (int*)alloc((size_t)N_NODES * 4);
  float* ALS2     = (float*)alloc((size_t)N_NODES * 4);
  float* ALD2     = (float*)alloc((size_t)N_NODES * 4);
  size_t zero_span = off;
  int* rowptr     = (int*)alloc((size_t)(N_NODES + 1) * 4);
  int* scantmp    = (int*)alloc((size_t)N_NODES * 4);
  int* bsum       = (int*)alloc((size_t)SCAN_NBLKS * 4);
  int* colsrc     = (int*)alloc((size_t)NET * 4);
  ushort_t* W1t   = (ushort_t*)alloc((size_t)C1 * F_IN * 2);
  ushort_t* W2t   = (ushort_t*)alloc((size_t)F_OUT * C1 * 2);
  schar_t* H1q    = (schar_t*)alloc((size_t)N_NODES * C1);        // 12.8MB int8
  float* SC1      = (float*)alloc((size_t)N_NODES * HEADS * 4);   // 800KB scales
  float* ALS1     = (float*)alloc((size_t)N_NODES * HEADS * 4);
  float* ALD1     = (float*)alloc((size_t)N_NODES * HEADS * 4);
  ushort_t* X2b   = (ushort_t*)alloc((size_t)N_NODES * C1 * 2);
  ushort_t* H2b = (ushort_t*)H1q;  // H1 dead after agg1; 12.8MB each

  hipMemsetAsync(ws, 0, zero_span, stream);

  // CSR build
  count_deg<<<(NET + 255) / 256, 256, 0, stream>>>(EI, deg);
  scan_blocks<<<SCAN_NBLKS, 256, 0, stream>>>(deg, scantmp, bsum);
  scan_bsum<<<1, 256, 0, stream>>>(bsum);
  finalize_rowptr<<<SCAN_NBLKS, 256, 0, stream>>>(scantmp, bsum, rowptr);
  scatter_edges<<<(NET + 255) / 256, 256, 0, stream>>>(EI, rowptr, fill, colsrc);

  // weight transposes (bf16), single launch
  transpose_both<<<(F_IN * C1 + C1 * F_OUT + 255) / 256, 256, 0, stream>>>(W1, W1t, W2, W2t);

  // layer 1 (A = fp32 X converted in staging; C = int8 + per-(node,head) scale)
  {
    dim3 grid(C1 / 128, (N_NODES + 127) / 128);
    gemm_mfma<F_IN, C1, 1, float, schar_t><<<grid, 256, 0, stream>>>(
        X, W1t, H1q, SC1, a1s, a1d, ALS1, ALD1);
  }
  agg1<<<(N_NODES + 3) / 4, 256, 0, stream>>>(rowptr, colsrc, H1q, SC1, ALS1, ALD1, b1, X2b);

  // layer 2 (bf16 throughout)
  {
    dim3 grid(F_OUT / 128, (N_NODES + 127) / 128);
    gemm_mfma<C1, F_OUT, 2, ushort_t, ushort_t><<<grid, 256, 0, stream>>>(
        X2b, W2t, H2b, nullptr, a2s, a2d, ALS2, ALD2);
  }
  agg2<<<(N_NODES + 3) / 4, 256, 0, stream>>>(rowptr, colsrc, H2b, ALS2, ALD2, b2, out);
}

// Round 14
// 207.173 us; speedup vs baseline: 2.1079x; 1.0952x over previous
//
#include <hip/hip_runtime.h>
#include <math.h>

#define N_NODES 50000
#define F_IN    128
#define HIDC    64
#define HEADS   4
#define C1      (HEADS*HIDC)   // 256
#define F_OUT   128
#define NE      800000
#define NET     (NE + N_NODES) // 850000 edges incl self-loops
#define NEG_SLOPE 0.2f

#define NPB   49               // nodes per bucket
#define NBUCK 1021             // ceil(N_NODES / NPB)
#define BPAD  16               // counter padding (ints): 1 counter per 64B line
#define K4CAP 2048             // LDS staging cap (mean 833, 6-sigma safe)

typedef unsigned short ushort_t;
typedef signed char    schar_t;
typedef __attribute__((ext_vector_type(8))) short bf16x8;
typedef __attribute__((ext_vector_type(8))) unsigned short us8;
typedef __attribute__((ext_vector_type(4))) float f32x4;

__device__ __forceinline__ float b2f(ushort_t x) {
  return __uint_as_float(((unsigned int)x) << 16);
}
__device__ __forceinline__ ushort_t f2bf(float f) {  // RNE, no NaN expected
  unsigned int u = __float_as_uint(f);
  return (ushort_t)((u + 0x7fffu + ((u >> 16) & 1u)) >> 16);
}
__device__ __forceinline__ float u2f_lo(unsigned int u) { return __uint_as_float(u << 16); }
__device__ __forceinline__ float u2f_hi(unsigned int u) { return __uint_as_float(u & 0xffff0000u); }

__device__ __forceinline__ void fma8v(float ww, uint4 vv, float* a) {  // bf16 x8
  a[0] = fmaf(ww, u2f_lo(vv.x), a[0]); a[1] = fmaf(ww, u2f_hi(vv.x), a[1]);
  a[2] = fmaf(ww, u2f_lo(vv.y), a[2]); a[3] = fmaf(ww, u2f_hi(vv.y), a[3]);
  a[4] = fmaf(ww, u2f_lo(vv.z), a[4]); a[5] = fmaf(ww, u2f_hi(vv.z), a[5]);
  a[6] = fmaf(ww, u2f_lo(vv.w), a[6]); a[7] = fmaf(ww, u2f_hi(vv.w), a[7]);
}
// int8 x8 decode: wsc = w * scale folded; denominator uses raw w.
__device__ __forceinline__ void fma8q(float wsc, uint2 vv, float* a) {
  int x = (int)vv.x, y = (int)vv.y;
  a[0] = fmaf(wsc, (float)(schar_t)(x),        a[0]);
  a[1] = fmaf(wsc, (float)(schar_t)(x >> 8),   a[1]);
  a[2] = fmaf(wsc, (float)(schar_t)(x >> 16),  a[2]);
  a[3] = fmaf(wsc, (float)(x >> 24),           a[3]);
  a[4] = fmaf(wsc, (float)(schar_t)(y),        a[4]);
  a[5] = fmaf(wsc, (float)(schar_t)(y >> 8),   a[5]);
  a[6] = fmaf(wsc, (float)(schar_t)(y >> 16),  a[6]);
  a[7] = fmaf(wsc, (float)(y >> 24),           a[7]);
}

// ---------------- bucketed CSR build ----------------
// Buckets of NPB consecutive dst nodes; counting sort gives write locality:
// final colsrc writes land in a ~3.3KB window per block (vs 4B random scatter
// whose 16x line amplification made round-13's scatter_edges run at 1.2TB/s).

__global__ __launch_bounds__(256) void bucket_count(const int* __restrict__ ei,
                                                    int* __restrict__ bcnt) {
  __shared__ int hist[NBUCK];
  for (int i = threadIdx.x; i < NBUCK; i += 256) hist[i] = 0;
  __syncthreads();
  int stride = gridDim.x * 256;
  for (int e = blockIdx.x * 256 + threadIdx.x; e < NET; e += stride) {
    int d = (e < NE) ? ei[NE + e] : (e - NE);
    atomicAdd(&hist[d / NPB], 1);
  }
  __syncthreads();
  for (int i = threadIdx.x; i < NBUCK; i += 256)
    if (hist[i]) atomicAdd(&bcnt[i * BPAD], hist[i]);
}

__global__ __launch_bounds__(1024) void scan_buckets(const int* __restrict__ bcnt,
                                                     int* __restrict__ boff) {
  __shared__ int sh[1024];
  int t = threadIdx.x;
  sh[t] = (t < NBUCK) ? bcnt[t * BPAD] : 0;
  __syncthreads();
#pragma unroll
  for (int off = 1; off < 1024; off <<= 1) {
    int u = (t >= off) ? sh[t - off] : 0;
    __syncthreads();
    sh[t] += u;
    __syncthreads();
  }
  if (t < NBUCK) boff[t + 1] = sh[t];
  if (t == 0) boff[0] = 0;
}

__global__ void bucket_scatter(const int* __restrict__ ei, const int* __restrict__ boff,
                               int* __restrict__ bfill, int2* __restrict__ pairs) {
  int e = blockIdx.x * blockDim.x + threadIdx.x;
  if (e >= NET) return;
  int s, d;
  if (e < NE) { s = ei[e]; d = ei[NE + e]; }
  else        { s = e - NE; d = s; }
  int b = d / NPB;
  int pos = atomicAdd(&bfill[b * BPAD], 1);
  pairs[boff[b] + pos] = make_int2(s, d);
}

// one block per bucket: local CSR (rowptr from LDS scan) + locality-friendly colsrc.
__global__ __launch_bounds__(256) void build_csr(const int2* __restrict__ pairs,
                                                 const int* __restrict__ boff,
                                                 int* __restrict__ rowptr,
                                                 int* __restrict__ colsrc) {
  __shared__ int cnt[NPB];
  __shared__ int loc[NPB + 1];
  __shared__ int2 buf[K4CAP];
  int b = blockIdx.x, t = threadIdx.x;
  int p0 = boff[b], p1 = boff[b + 1];
  int m = p1 - p0;
  int n0 = b * NPB;
  int nn = min(NPB, N_NODES - n0);
  for (int i = t; i < NPB; i += 256) cnt[i] = 0;
  __syncthreads();
  bool inlds = (m <= K4CAP);
  for (int i = t; i < m; i += 256) {
    int2 p = pairs[p0 + i];
    if (inlds) buf[i] = p;
    atomicAdd(&cnt[p.y - n0], 1);
  }
  __syncthreads();
  if (t == 0) {
    int run = 0;
#pragma unroll 1
    for (int j = 0; j < nn; ++j) { loc[j] = run; run += cnt[j]; }
    loc[nn] = run;   // == m
  }
  __syncthreads();
  for (int j = t; j < nn; j += 256) rowptr[n0 + j] = p0 + loc[j];
  if (t == 0 && n0 + nn == N_NODES) rowptr[N_NODES] = NET;
  // reuse cnt as fill
  for (int i = t; i < NPB; i += 256) cnt[i] = 0;
  __syncthreads();
  for (int i = t; i < m; i += 256) {
    int2 p = inlds ? buf[i] : pairs[p0 + i];
    int j = p.y - n0;
    int pos = atomicAdd(&cnt[j], 1);
    colsrc[p0 + loc[j] + pos] = p.x;
  }
}

// ---------------- setup: both weight transposes in one kernel ----------------

__global__ void transpose_both(const float* __restrict__ W1, ushort_t* __restrict__ W1t,
                               const float* __restrict__ W2, ushort_t* __restrict__ W2t) {
  int idx = blockIdx.x * blockDim.x + threadIdx.x;
  if (idx < F_IN * C1) {
    int k = idx / C1, n = idx - k * C1;
    W1t[(size_t)n * F_IN + k] = f2bf(W1[idx]);
  } else {
    int j = idx - F_IN * C1;
    if (j < C1 * F_OUT) {
      int k = j / F_OUT, n = j - k * F_OUT;
      W2t[(size_t)n * C1 + k] = f2bf(W2[j]);
    }
  }
}

// ---------------- MFMA bf16 GEMM with fused AL-logit epilogue ----------------
// CT: schar_t -> int8 C + per-(node,head) scale (layer1); ushort_t -> bf16 C.

#define BKS 64
#define LDT 72

__device__ __forceinline__ us8 stage8(const ushort_t* p) { return *(const us8*)p; }
__device__ __forceinline__ us8 stage8(const float* p) {
  float4 f0 = *(const float4*)p;
  float4 f1 = *(const float4*)(p + 4);
  us8 o;
  o[0] = f2bf(f0.x); o[1] = f2bf(f0.y); o[2] = f2bf(f0.z); o[3] = f2bf(f0.w);
  o[4] = f2bf(f1.x); o[5] = f2bf(f1.y); o[6] = f2bf(f1.z); o[7] = f2bf(f1.w);
  return o;
}

template<int K, int NCOL, int AL_MODE, typename AT, typename CT>
__global__ __launch_bounds__(256) void gemm_mfma(const AT* __restrict__ A,
                                                 const ushort_t* __restrict__ Bt,
                                                 CT* __restrict__ C,
                                                 float* __restrict__ scales,
                                                 const float* __restrict__ a_s,
                                                 const float* __restrict__ a_d,
                                                 float* __restrict__ als,
                                                 float* __restrict__ ald) {
  __shared__ __align__(16) char smem[2 * 128 * LDT * 2];
  ushort_t (*Asl)[LDT] = (ushort_t(*)[LDT])smem;
  ushort_t (*Bsl)[LDT] = (ushort_t(*)[LDT])(smem + 128 * LDT * 2);

  const int tid = threadIdx.x;
  const int lane = tid & 63;
  const int wave = tid >> 6;
  const int wr = wave >> 1, wc = wave & 1;
  const int row0 = blockIdx.y * 128;
  const int col0 = blockIdx.x * 128;
  const int l15 = lane & 15, l4 = lane >> 4;

  f32x4 acc[4][4] = {};

  for (int k0 = 0; k0 < K; k0 += BKS) {
#pragma unroll
    for (int i = 0; i < 4; ++i) {
      int seg = tid + i * 256;
      int row = seg >> 3, kq = (seg & 7) * 8;
      int arow = row0 + row;
      us8 v = {0, 0, 0, 0, 0, 0, 0, 0};
      if (arow < N_NODES) v = stage8(&A[(size_t)arow * K + k0 + kq]);
      *(us8*)&Asl[row][kq] = v;
    }
#pragma unroll
    for (int i = 0; i < 4; ++i) {
      int seg = tid + i * 256;
      int row = seg >> 3, kq = (seg & 7) * 8;
      us8 v = *(const us8*)&Bt[(size_t)(col0 + row) * K + k0 + kq];
      *(us8*)&Bsl[row][kq] = v;
    }
    __syncthreads();
#pragma unroll
    for (int kk = 0; kk < BKS; kk += 32) {
      bf16x8 af[4], bfr[4];
#pragma unroll
      for (int mi = 0; mi < 4; ++mi)
        af[mi] = *(const bf16x8*)&Asl[wr * 64 + mi * 16 + l15][kk + l4 * 8];
#pragma unroll
      for (int ni = 0; ni < 4; ++ni)
        bfr[ni] = *(const bf16x8*)&Bsl[wc * 64 + ni * 16 + l15][kk + l4 * 8];
#pragma unroll
      for (int mi = 0; mi < 4; ++mi)
#pragma unroll
        for (int ni = 0; ni < 4; ++ni)
          acc[mi][ni] = __builtin_amdgcn_mfma_f32_16x16x32_bf16(af[mi], bfr[ni], acc[mi][ni], 0, 0, 0);
    }
    __syncthreads();
  }

  // ---- fused attention-logit dots ----
  {
    const int albase = (AL_MODE == 1 ? col0 : 0) + wc * 64;
    float asv[4], adv[4];
#pragma unroll
    for (int ni = 0; ni < 4; ++ni) {
      asv[ni] = a_s[albase + ni * 16 + l15];
      adv[ni] = a_d[albase + ni * 16 + l15];
    }
#pragma unroll
    for (int mi = 0; mi < 4; ++mi) {
      float ps[4], pd[4];
#pragma unroll
      for (int r = 0; r < 4; ++r) {
        ps[r] = acc[mi][0][r] * asv[0] + acc[mi][1][r] * asv[1] +
                acc[mi][2][r] * asv[2] + acc[mi][3][r] * asv[3];
        pd[r] = acc[mi][0][r] * adv[0] + acc[mi][1][r] * adv[1] +
                acc[mi][2][r] * adv[2] + acc[mi][3][r] * adv[3];
      }
#pragma unroll
      for (int m = 1; m < 16; m <<= 1) {
#pragma unroll
        for (int r = 0; r < 4; ++r) {
          ps[r] += __shfl_xor(ps[r], m, 64);
          pd[r] += __shfl_xor(pd[r], m, 64);
        }
      }
      if (l15 == 0) {
#pragma unroll
        for (int r = 0; r < 4; ++r) {
          int row = row0 + wr * 64 + mi * 16 + l4 * 4 + r;
          if (row < N_NODES) {
            if (AL_MODE == 1) {
              int h = albase >> 6;
              als[row * 4 + h] = ps[r];
              ald[row * 4 + h] = pd[r];
            } else {
              atomicAdd(&als[row], ps[r]);
              atomicAdd(&ald[row], pd[r]);
            }
          }
        }
      }
    }
  }

  // ---- C epilogue: acc -> LDS bf16 bounce -> global (int8+scale or bf16) ----
  {
    ushort_t (*Ep)[136] = (ushort_t(*)[136])smem;
#pragma unroll
    for (int mi = 0; mi < 4; ++mi)
#pragma unroll
      for (int ni = 0; ni < 4; ++ni)
#pragma unroll
        for (int r = 0; r < 4; ++r)
          Ep[wr * 64 + mi * 16 + l4 * 4 + r][wc * 64 + ni * 16 + l15] = f2bf(acc[mi][ni][r]);
    __syncthreads();
    int row = tid >> 1, half = tid & 1;
    int grow = row0 + row;
    if (grow < N_NODES) {
      if constexpr (sizeof(CT) == 1) {
        float vals[64];
        float amax = 0.f;
#pragma unroll
        for (int i = 0; i < 8; ++i) {
          us8 v = *(const us8*)&Ep[row][half * 64 + i * 8];
#pragma unroll
          for (int j = 0; j < 8; ++j) {
            float f = b2f((ushort_t)v[j]);
            vals[i * 8 + j] = f;
            amax = fmaxf(amax, fabsf(f));
          }
        }
        float inv = amax > 0.f ? 127.f / amax : 0.f;
        scales[grow * 4 + (col0 >> 6) + half] = amax * (1.f / 127.f);
        schar_t ob[64];
#pragma unroll
        for (int i = 0; i < 64; ++i)
          ob[i] = (schar_t)(int)rintf(vals[i] * inv);
#pragma unroll
        for (int i = 0; i < 4; ++i)
          *(us8*)&C[(size_t)grow * NCOL + col0 + half * 64 + i * 16] =
              *(const us8*)&ob[i * 16];
      } else {
#pragma unroll
        for (int i = 0; i < 8; ++i)
          *(us8*)&C[(size_t)grow * NCOL + col0 + half * 64 + i * 8] =
              *(const us8*)&Ep[row][half * 64 + i * 8];
      }
    }
  }
}

// ---------------- fused softmax + gather aggregation ----------------

// layer1: int8 messages + per-(node,head) scale; half-wave per edge, 4 in flight/half.
__global__ __launch_bounds__(256) void agg1(const int* __restrict__ rowptr,
                                            const int* __restrict__ colsrc,
                                            const schar_t* __restrict__ Hq,
                                            const float* __restrict__ Sc,
                                            const float* __restrict__ als,
                                            const float* __restrict__ ald,
                                            const float* __restrict__ b1,
                                            ushort_t* __restrict__ X2b) {
  int wave = threadIdx.x >> 6, lane = threadIdx.x & 63;
  int n = blockIdx.x * 4 + wave;
  if (n >= N_NODES) return;
  int half = lane >> 5, li = lane & 31, h = li >> 3;
  float ad = ald[n * 4 + h];
  int beg = rowptr[n], end = rowptr[n + 1];
  float a[8] = {};
  float s = 0.f;
  int i = beg + half;
  for (; i + 6 < end; i += 8) {
    int s0 = colsrc[i], s1 = colsrc[i + 2], s2 = colsrc[i + 4], s3 = colsrc[i + 6];
    float sc0 = als[s0 * 4 + h] + ad;
    float sc1 = als[s1 * 4 + h] + ad;
    float sc2 = als[s2 * 4 + h] + ad;
    float sc3 = als[s3 * 4 + h] + ad;
    float q0 = Sc[s0 * 4 + h], q1 = Sc[s1 * 4 + h], q2 = Sc[s2 * 4 + h], q3 = Sc[s3 * 4 + h];
    uint2 v0 = *(const uint2*)&Hq[(size_t)s0 * C1 + li * 8];
    uint2 v1 = *(const uint2*)&Hq[(size_t)s1 * C1 + li * 8];
    uint2 v2 = *(const uint2*)&Hq[(size_t)s2 * C1 + li * 8];
    uint2 v3 = *(const uint2*)&Hq[(size_t)s3 * C1 + li * 8];
    sc0 = sc0 > 0.f ? sc0 : NEG_SLOPE * sc0;
    sc1 = sc1 > 0.f ? sc1 : NEG_SLOPE * sc1;
    sc2 = sc2 > 0.f ? sc2 : NEG_SLOPE * sc2;
    sc3 = sc3 > 0.f ? sc3 : NEG_SLOPE * sc3;
    float w0 = __expf(sc0), w1 = __expf(sc1), w2 = __expf(sc2), w3 = __expf(sc3);
    s += (w0 + w1) + (w2 + w3);
    fma8q(w0 * q0, v0, a); fma8q(w1 * q1, v1, a);
    fma8q(w2 * q2, v2, a); fma8q(w3 * q3, v3, a);
  }
  for (; i + 2 < end; i += 4) {
    int s0 = colsrc[i], s1 = colsrc[i + 2];
    float sc0 = als[s0 * 4 + h] + ad;
    float sc1 = als[s1 * 4 + h] + ad;
    float q0 = Sc[s0 * 4 + h], q1 = Sc[s1 * 4 + h];
    uint2 v0 = *(const uint2*)&Hq[(size_t)s0 * C1 + li * 8];
    uint2 v1 = *(const uint2*)&Hq[(size_t)s1 * C1 + li * 8];
    sc0 = sc0 > 0.f ? sc0 : NEG_SLOPE * sc0;
    sc1 = sc1 > 0.f ? sc1 : NEG_SLOPE * sc1;
    float w0 = __expf(sc0), w1 = __expf(sc1);
    s += w0 + w1;
    fma8q(w0 * q0, v0, a); fma8q(w1 * q1, v1, a);
  }
  for (; i < end; i += 2) {
    int s0 = colsrc[i];
    float sc0 = als[s0 * 4 + h] + ad;
    float q0 = Sc[s0 * 4 + h];
    uint2 v0 = *(const uint2*)&Hq[(size_t)s0 * C1 + li * 8];
    sc0 = sc0 > 0.f ? sc0 : NEG_SLOPE * sc0;
    float w0 = __expf(sc0);
    s += w0;
    fma8q(w0 * q0, v0, a);
  }
#pragma unroll
  for (int j = 0; j < 8; ++j) a[j] += __shfl_xor(a[j], 32, 64);
  s += __shfl_xor(s, 32, 64);
  if (lane < 32) {
    float si = 1.f / s;
    int c = li * 8;
    float4 bb0 = *(const float4*)&b1[c];
    float4 bb1 = *(const float4*)&b1[c + 4];
    ushort_t o[8];
    o[0] = f2bf(fmaxf(a[0] * si + bb0.x, 0.f));
    o[1] = f2bf(fmaxf(a[1] * si + bb0.y, 0.f));
    o[2] = f2bf(fmaxf(a[2] * si + bb0.z, 0.f));
    o[3] = f2bf(fmaxf(a[3] * si + bb0.w, 0.f));
    o[4] = f2bf(fmaxf(a[4] * si + bb1.x, 0.f));
    o[5] = f2bf(fmaxf(a[5] * si + bb1.y, 0.f));
    o[6] = f2bf(fmaxf(a[6] * si + bb1.z, 0.f));
    o[7] = f2bf(fmaxf(a[7] * si + bb1.w, 0.f));
    *(us8*)&X2b[(size_t)n * C1 + c] = *(const us8*)o;
  }
}

// layer2: bf16 rows; quarter-wave per edge; 4 in flight per quarter.
__global__ __launch_bounds__(256) void agg2(const int* __restrict__ rowptr,
                                            const int* __restrict__ colsrc,
                                            const ushort_t* __restrict__ Hb,
                                            const float* __restrict__ als,
                                            const float* __restrict__ ald,
                                            const float* __restrict__ b2,
                                            float* __restrict__ out) {
  int wave = threadIdx.x >> 6, lane = threadIdx.x & 63;
  int n = blockIdx.x * 4 + wave;
  if (n >= N_NODES) return;
  int quarter = lane >> 4, li = lane & 15;
  float ad = ald[n];
  int beg = rowptr[n], end = rowptr[n + 1];
  float a[8] = {};
  float s = 0.f;
  int i = beg + quarter;
  for (; i + 12 < end; i += 16) {
    int s0 = colsrc[i], s1 = colsrc[i + 4], s2 = colsrc[i + 8], s3 = colsrc[i + 12];
    float sc0 = als[s0] + ad;
    float sc1 = als[s1] + ad;
    float sc2 = als[s2] + ad;
    float sc3 = als[s3] + ad;
    uint4 v0 = *(const uint4*)&Hb[(size_t)s0 * F_OUT + li * 8];
    uint4 v1 = *(const uint4*)&Hb[(size_t)s1 * F_OUT + li * 8];
    uint4 v2 = *(const uint4*)&Hb[(size_t)s2 * F_OUT + li * 8];
    uint4 v3 = *(const uint4*)&Hb[(size_t)s3 * F_OUT + li * 8];
    sc0 = sc0 > 0.f ? sc0 : NEG_SLOPE * sc0;
    sc1 = sc1 > 0.f ? sc1 : NEG_SLOPE * sc1;
    sc2 = sc2 > 0.f ? sc2 : NEG_SLOPE * sc2;
    sc3 = sc3 > 0.f ? sc3 : NEG_SLOPE * sc3;
    float w0 = __expf(sc0), w1 = __expf(sc1), w2 = __expf(sc2), w3 = __expf(sc3);
    s += (w0 + w1) + (w2 + w3);
    fma8v(w0, v0, a); fma8v(w1, v1, a); fma8v(w2, v2, a); fma8v(w3, v3, a);
  }
  for (; i + 4 < end; i += 8) {
    int s0 = colsrc[i], s1 = colsrc[i + 4];
    float sc0 = als[s0] + ad;
    float sc1 = als[s1] + ad;
    uint4 v0 = *(const uint4*)&Hb[(size_t)s0 * F_OUT + li * 8];
    uint4 v1 = *(const uint4*)&Hb[(size_t)s1 * F_OUT + li * 8];
    sc0 = sc0 > 0.f ? sc0 : NEG_SLOPE * sc0;
    sc1 = sc1 > 0.f ? sc1 : NEG_SLOPE * sc1;
    float w0 = __expf(sc0), w1 = __expf(sc1);
    s += w0 + w1;
    fma8v(w0, v0, a); fma8v(w1, v1, a);
  }
  for (; i < end; i += 4) {
    int s0 = colsrc[i];
    float sc0 = als[s0] + ad;
    uint4 v0 = *(const uint4*)&Hb[(size_t)s0 * F_OUT + li * 8];
    sc0 = sc0 > 0.f ? sc0 : NEG_SLOPE * sc0;
    float w0 = __expf(sc0);
    s += w0;
    fma8v(w0, v0, a);
  }
#pragma unroll
  for (int j = 0; j < 8; ++j) a[j] += __shfl_xor(a[j], 16, 64);
#pragma unroll
  for (int j = 0; j < 8; ++j) a[j] += __shfl_xor(a[j], 32, 64);
  s += __shfl_xor(s, 16, 64);
  s += __shfl_xor(s, 32, 64);
  if (lane < 16) {
    float si = 1.f / s;
    int c = li * 8;
    float4 bb0 = *(const float4*)&b2[c];
    float4 bb1 = *(const float4*)&b2[c + 4];
    float4 o0, o1;
    o0.x = a[0] * si + bb0.x; o0.y = a[1] * si + bb0.y;
    o0.z = a[2] * si + bb0.z; o0.w = a[3] * si + bb0.w;
    o1.x = a[4] * si + bb1.x; o1.y = a[5] * si + bb1.y;
    o1.z = a[6] * si + bb1.z; o1.w = a[7] * si + bb1.w;
    *(float4*)&out[(size_t)n * F_OUT + c] = o0;
    *(float4*)&out[(size_t)n * F_OUT + c + 4] = o1;
  }
}

// ---------------- launch ----------------

extern "C" void kernel_launch(void* const* d_in, const int* in_sizes, int n_in,
                              void* d_out, int out_size, void* d_ws, size_t ws_size,
                              hipStream_t stream) {
  const float* X   = (const float*)d_in[0];
  const int*   EI  = (const int*)d_in[1];
  const float* W1  = (const float*)d_in[2];
  const float* a1s = (const float*)d_in[3];
  const float* a1d = (const float*)d_in[4];
  const float* b1  = (const float*)d_in[5];
  const float* W2  = (const float*)d_in[6];
  const float* a2s = (const float*)d_in[7];
  const float* a2d = (const float*)d_in[8];
  const float* b2  = (const float*)d_in[9];
  float* out = (float*)d_out;

  char* ws = (char*)d_ws;
  size_t off = 0;
  auto alloc = [&](size_t bytes) -> void* {
    void* p = ws + off;
    off += (bytes + 255) & ~(size_t)255;
    return p;
  };
  // zero-init block first (single memset)
  int* bcnt       = (int*)alloc((size_t)NBUCK * BPAD * 4);   // 65KB padded counters
  int* bfill      = (int*)alloc((size_t)NBUCK * BPAD * 4);
  float* ALS2     = (float*)alloc((size_t)N_NODES * 4);
  float* ALD2     = (float*)alloc((size_t)N_NODES * 4);
  size_t zero_span = off;
  int* boff       = (int*)alloc((size_t)(NBUCK + 1) * 4);
  int* rowptr     = (int*)alloc((size_t)(N_NODES + 1) * 4);
  int* colsrc     = (int*)alloc((size_t)NET * 4);
  int2* pairs     = (int2*)alloc((size_t)NET * 8);           // 6.8MB
  ushort_t* W1t   = (ushort_t*)alloc((size_t)C1 * F_IN * 2);
  ushort_t* W2t   = (ushort_t*)alloc((size_t)F_OUT * C1 * 2);
  schar_t* H1q    = (schar_t*)alloc((size_t)N_NODES * C1);        // 12.8MB int8
  float* SC1      = (float*)alloc((size_t)N_NODES * HEADS * 4);   // 800KB scales
  float* ALS1     = (float*)alloc((size_t)N_NODES * HEADS * 4);
  float* ALD1     = (float*)alloc((size_t)N_NODES * HEADS * 4);
  ushort_t* X2b   = (ushort_t*)alloc((size_t)N_NODES * C1 * 2);
  ushort_t* H2b = (ushort_t*)H1q;  // H1 dead after agg1; 12.8MB each

  hipMemsetAsync(ws, 0, zero_span, stream);

  // bucketed CSR build
  bucket_count<<<128, 256, 0, stream>>>(EI, bcnt);
  scan_buckets<<<1, 1024, 0, stream>>>(bcnt, boff);
  bucket_scatter<<<(NET + 255) / 256, 256, 0, stream>>>(EI, boff, bfill, pairs);
  build_csr<<<NBUCK, 256, 0, stream>>>(pairs, boff, rowptr, colsrc);

  // weight transposes (bf16), single launch
  transpose_both<<<(F_IN * C1 + C1 * F_OUT + 255) / 256, 256, 0, stream>>>(W1, W1t, W2, W2t);

  // layer 1 (A = fp32 X converted in staging; C = int8 + per-(node,head) scale)
  {
    dim3 grid(C1 / 128, (N_NODES + 127) / 128);
    gemm_mfma<F_IN, C1, 1, float, schar_t><<<grid, 256, 0, stream>>>(
        X, W1t, H1q, SC1, a1s, a1d, ALS1, ALD1);
  }
  agg1<<<(N_NODES + 3) / 4, 256, 0, stream>>>(rowptr, colsrc, H1q, SC1, ALS1, ALD1, b1, X2b);

  // layer 2 (bf16 throughout)
  {
    dim3 grid(F_OUT / 128, (N_NODES + 127) / 128);
    gemm_mfma<C1, F_OUT, 2, ushort_t, ushort_t><<<grid, 256, 0, stream>>>(
        X2b, W2t, H2b, nullptr, a2s, a2d, ALS2, ALD2);
  }
  agg2<<<(N_NODES + 3) / 4, 256, 0, stream>>>(rowptr, colsrc, H2b, ALS2, ALD2, b2, out);
}

// Round 15
// 176.024 us; speedup vs baseline: 2.4810x; 1.1770x over previous
//
#include <hip/hip_runtime.h>
#include <math.h>

#define N_NODES 50000
#define F_IN    128
#define HIDC    64
#define HEADS   4
#define C1      (HEADS*HIDC)   // 256
#define F_OUT   128
#define NE      800000
#define NET     (NE + N_NODES) // 850000 edges incl self-loops
#define NEG_SLOPE 0.2f

#define NPB   49               // nodes per bucket
#define NBUCK 1021             // ceil(N_NODES / NPB)
#define BPAD  16               // counter padding (ints): 1 counter per 64B line
#define K4CAP 2048             // build_csr LDS staging cap (mean 833)
#define SCHUNK 8192            // edges per scatter block (run ~8 pairs = 1 line/bucket)

typedef unsigned short ushort_t;
typedef signed char    schar_t;
typedef __attribute__((ext_vector_type(8))) short bf16x8;
typedef __attribute__((ext_vector_type(8))) unsigned short us8;
typedef __attribute__((ext_vector_type(4))) float f32x4;

__device__ __forceinline__ float b2f(ushort_t x) {
  return __uint_as_float(((unsigned int)x) << 16);
}
__device__ __forceinline__ ushort_t f2bf(float f) {  // RNE, no NaN expected
  unsigned int u = __float_as_uint(f);
  return (ushort_t)((u + 0x7fffu + ((u >> 16) & 1u)) >> 16);
}
__device__ __forceinline__ float u2f_lo(unsigned int u) { return __uint_as_float(u << 16); }
__device__ __forceinline__ float u2f_hi(unsigned int u) { return __uint_as_float(u & 0xffff0000u); }

__device__ __forceinline__ void fma8v(float ww, uint4 vv, float* a) {  // bf16 x8
  a[0] = fmaf(ww, u2f_lo(vv.x), a[0]); a[1] = fmaf(ww, u2f_hi(vv.x), a[1]);
  a[2] = fmaf(ww, u2f_lo(vv.y), a[2]); a[3] = fmaf(ww, u2f_hi(vv.y), a[3]);
  a[4] = fmaf(ww, u2f_lo(vv.z), a[4]); a[5] = fmaf(ww, u2f_hi(vv.z), a[5]);
  a[6] = fmaf(ww, u2f_lo(vv.w), a[6]); a[7] = fmaf(ww, u2f_hi(vv.w), a[7]);
}
// int8 x8 decode: wsc = w * scale folded; denominator uses raw w.
__device__ __forceinline__ void fma8q(float wsc, uint2 vv, float* a) {
  int x = (int)vv.x, y = (int)vv.y;
  a[0] = fmaf(wsc, (float)(schar_t)(x),        a[0]);
  a[1] = fmaf(wsc, (float)(schar_t)(x >> 8),   a[1]);
  a[2] = fmaf(wsc, (float)(schar_t)(x >> 16),  a[2]);
  a[3] = fmaf(wsc, (float)(x >> 24),           a[3]);
  a[4] = fmaf(wsc, (float)(schar_t)(y),        a[4]);
  a[5] = fmaf(wsc, (float)(schar_t)(y >> 8),   a[5]);
  a[6] = fmaf(wsc, (float)(schar_t)(y >> 16),  a[6]);
  a[7] = fmaf(wsc, (float)(y >> 24),           a[7]);
}

// ---------------- bucketed CSR build ----------------

__global__ __launch_bounds__(256) void bucket_count(const int* __restrict__ ei,
                                                    int* __restrict__ bcnt) {
  __shared__ int hist[NBUCK];
  for (int i = threadIdx.x; i < NBUCK; i += 256) hist[i] = 0;
  __syncthreads();
  int stride = gridDim.x * 256;
  for (int e = blockIdx.x * 256 + threadIdx.x; e < NET; e += stride) {
    int d = (e < NE) ? ei[NE + e] : (e - NE);
    atomicAdd(&hist[d / NPB], 1);
  }
  __syncthreads();
  for (int i = threadIdx.x; i < NBUCK; i += 256)
    if (hist[i]) atomicAdd(&bcnt[i * BPAD], hist[i]);
}

__global__ __launch_bounds__(1024) void scan_buckets(const int* __restrict__ bcnt,
                                                     int* __restrict__ boff) {
  __shared__ int sh[1024];
  int t = threadIdx.x;
  sh[t] = (t < NBUCK) ? bcnt[t * BPAD] : 0;
  __syncthreads();
#pragma unroll
  for (int off = 1; off < 1024; off <<= 1) {
    int u = (t >= off) ? sh[t - off] : 0;
    __syncthreads();
    sh[t] += u;
    __syncthreads();
  }
  if (t < NBUCK) boff[t + 1] = sh[t];
  if (t == 0) boff[0] = 0;
}

// Block-owned runs: each block histograms its 8192-edge chunk, reserves one
// contiguous run per bucket (global atomicAdd of the whole count), then fills
// the run itself. Every 64B pairs-line is written by ONE block on ONE XCD ->
// L2 assembles full lines; kills round-14's 7x write amplification.
__global__ __launch_bounds__(1024) void bucket_scatter_blocked(const int* __restrict__ ei,
                                                               const int* __restrict__ boff,
                                                               int* __restrict__ bfill,
                                                               int2* __restrict__ pairs) {
  __shared__ int hist[NBUCK];
  __shared__ int gbase[NBUCK];
  __shared__ int fill[NBUCK];
  int c0 = blockIdx.x * SCHUNK;
  int cend = min(c0 + SCHUNK, NET);
  for (int i = threadIdx.x; i < NBUCK; i += 1024) { hist[i] = 0; fill[i] = 0; }
  __syncthreads();
  for (int e = c0 + threadIdx.x; e < cend; e += 1024) {
    int d = (e < NE) ? ei[NE + e] : (e - NE);
    atomicAdd(&hist[d / NPB], 1);
  }
  __syncthreads();
  for (int i = threadIdx.x; i < NBUCK; i += 1024)
    if (hist[i]) gbase[i] = boff[i] + atomicAdd(&bfill[i * BPAD], hist[i]);
  __syncthreads();
  for (int e = c0 + threadIdx.x; e < cend; e += 1024) {
    int s, d;
    if (e < NE) { s = ei[e]; d = ei[NE + e]; }
    else        { s = e - NE; d = s; }
    int b = d / NPB;
    int lpos = atomicAdd(&fill[b], 1);
    pairs[gbase[b] + lpos] = make_int2(s, d);
  }
}

// one block per bucket: local CSR + locality-friendly colsrc writes.
__global__ __launch_bounds__(256) void build_csr(const int2* __restrict__ pairs,
                                                 const int* __restrict__ boff,
                                                 int* __restrict__ rowptr,
                                                 int* __restrict__ colsrc) {
  __shared__ int cnt[NPB];
  __shared__ int loc[NPB + 1];
  __shared__ int2 buf[K4CAP];
  int b = blockIdx.x, t = threadIdx.x;
  int p0 = boff[b], p1 = boff[b + 1];
  int m = p1 - p0;
  int n0 = b * NPB;
  int nn = min(NPB, N_NODES - n0);
  for (int i = t; i < NPB; i += 256) cnt[i] = 0;
  __syncthreads();
  bool inlds = (m <= K4CAP);
  for (int i = t; i < m; i += 256) {
    int2 p = pairs[p0 + i];
    if (inlds) buf[i] = p;
    atomicAdd(&cnt[p.y - n0], 1);
  }
  __syncthreads();
  if (t == 0) {
    int run = 0;
#pragma unroll 1
    for (int j = 0; j < nn; ++j) { loc[j] = run; run += cnt[j]; }
    loc[nn] = run;
  }
  __syncthreads();
  for (int j = t; j < nn; j += 256) rowptr[n0 + j] = p0 + loc[j];
  if (t == 0 && n0 + nn == N_NODES) rowptr[N_NODES] = NET;
  for (int i = t; i < NPB; i += 256) cnt[i] = 0;
  __syncthreads();
  for (int i = t; i < m; i += 256) {
    int2 p = inlds ? buf[i] : pairs[p0 + i];
    int j = p.y - n0;
    int pos = atomicAdd(&cnt[j], 1);
    colsrc[p0 + loc[j] + pos] = p.x;
  }
}

// ---------------- setup: both weight transposes in one kernel ----------------

__global__ void transpose_both(const float* __restrict__ W1, ushort_t* __restrict__ W1t,
                               const float* __restrict__ W2, ushort_t* __restrict__ W2t) {
  int idx = blockIdx.x * blockDim.x + threadIdx.x;
  if (idx < F_IN * C1) {
    int k = idx / C1, n = idx - k * C1;
    W1t[(size_t)n * F_IN + k] = f2bf(W1[idx]);
  } else {
    int j = idx - F_IN * C1;
    if (j < C1 * F_OUT) {
      int k = j / F_OUT, n = j - k * F_OUT;
      W2t[(size_t)n * C1 + k] = f2bf(W2[j]);
    }
  }
}

// ---------------- MFMA bf16 GEMM with fused AL-logit epilogue ----------------
// CT: schar_t -> int8 C + per-(node,head) scale (layer1); ushort_t -> bf16 C.

#define BKS 64
#define LDT 72

__device__ __forceinline__ us8 stage8(const ushort_t* p) { return *(const us8*)p; }
__device__ __forceinline__ us8 stage8(const float* p) {
  float4 f0 = *(const float4*)p;
  float4 f1 = *(const float4*)(p + 4);
  us8 o;
  o[0] = f2bf(f0.x); o[1] = f2bf(f0.y); o[2] = f2bf(f0.z); o[3] = f2bf(f0.w);
  o[4] = f2bf(f1.x); o[5] = f2bf(f1.y); o[6] = f2bf(f1.z); o[7] = f2bf(f1.w);
  return o;
}

template<int K, int NCOL, int AL_MODE, typename AT, typename CT>
__global__ __launch_bounds__(256) void gemm_mfma(const AT* __restrict__ A,
                                                 const ushort_t* __restrict__ Bt,
                                                 CT* __restrict__ C,
                                                 float* __restrict__ scales,
                                                 const float* __restrict__ a_s,
                                                 const float* __restrict__ a_d,
                                                 float* __restrict__ als,
                                                 float* __restrict__ ald) {
  __shared__ __align__(16) char smem[2 * 128 * LDT * 2];
  ushort_t (*Asl)[LDT] = (ushort_t(*)[LDT])smem;
  ushort_t (*Bsl)[LDT] = (ushort_t(*)[LDT])(smem + 128 * LDT * 2);

  const int tid = threadIdx.x;
  const int lane = tid & 63;
  const int wave = tid >> 6;
  const int wr = wave >> 1, wc = wave & 1;
  const int row0 = blockIdx.y * 128;
  const int col0 = blockIdx.x * 128;
  const int l15 = lane & 15, l4 = lane >> 4;

  f32x4 acc[4][4] = {};

  for (int k0 = 0; k0 < K; k0 += BKS) {
#pragma unroll
    for (int i = 0; i < 4; ++i) {
      int seg = tid + i * 256;
      int row = seg >> 3, kq = (seg & 7) * 8;
      int arow = row0 + row;
      us8 v = {0, 0, 0, 0, 0, 0, 0, 0};
      if (arow < N_NODES) v = stage8(&A[(size_t)arow * K + k0 + kq]);
      *(us8*)&Asl[row][kq] = v;
    }
#pragma unroll
    for (int i = 0; i < 4; ++i) {
      int seg = tid + i * 256;
      int row = seg >> 3, kq = (seg & 7) * 8;
      us8 v = *(const us8*)&Bt[(size_t)(col0 + row) * K + k0 + kq];
      *(us8*)&Bsl[row][kq] = v;
    }
    __syncthreads();
#pragma unroll
    for (int kk = 0; kk < BKS; kk += 32) {
      bf16x8 af[4], bfr[4];
#pragma unroll
      for (int mi = 0; mi < 4; ++mi)
        af[mi] = *(const bf16x8*)&Asl[wr * 64 + mi * 16 + l15][kk + l4 * 8];
#pragma unroll
      for (int ni = 0; ni < 4; ++ni)
        bfr[ni] = *(const bf16x8*)&Bsl[wc * 64 + ni * 16 + l15][kk + l4 * 8];
#pragma unroll
      for (int mi = 0; mi < 4; ++mi)
#pragma unroll
        for (int ni = 0; ni < 4; ++ni)
          acc[mi][ni] = __builtin_amdgcn_mfma_f32_16x16x32_bf16(af[mi], bfr[ni], acc[mi][ni], 0, 0, 0);
    }
    __syncthreads();
  }

  // ---- fused attention-logit dots ----
  {
    const int albase = (AL_MODE == 1 ? col0 : 0) + wc * 64;
    float asv[4], adv[4];
#pragma unroll
    for (int ni = 0; ni < 4; ++ni) {
      asv[ni] = a_s[albase + ni * 16 + l15];
      adv[ni] = a_d[albase + ni * 16 + l15];
    }
#pragma unroll
    for (int mi = 0; mi < 4; ++mi) {
      float ps[4], pd[4];
#pragma unroll
      for (int r = 0; r < 4; ++r) {
        ps[r] = acc[mi][0][r] * asv[0] + acc[mi][1][r] * asv[1] +
                acc[mi][2][r] * asv[2] + acc[mi][3][r] * asv[3];
        pd[r] = acc[mi][0][r] * adv[0] + acc[mi][1][r] * adv[1] +
                acc[mi][2][r] * adv[2] + acc[mi][3][r] * adv[3];
      }
#pragma unroll
      for (int m = 1; m < 16; m <<= 1) {
#pragma unroll
        for (int r = 0; r < 4; ++r) {
          ps[r] += __shfl_xor(ps[r], m, 64);
          pd[r] += __shfl_xor(pd[r], m, 64);
        }
      }
      if (l15 == 0) {
#pragma unroll
        for (int r = 0; r < 4; ++r) {
          int row = row0 + wr * 64 + mi * 16 + l4 * 4 + r;
          if (row < N_NODES) {
            if (AL_MODE == 1) {
              int h = albase >> 6;
              als[row * 4 + h] = ps[r];
              ald[row * 4 + h] = pd[r];
            } else {
              atomicAdd(&als[row], ps[r]);
              atomicAdd(&ald[row], pd[r]);
            }
          }
        }
      }
    }
  }

  // ---- C epilogue: acc -> LDS bf16 bounce -> global (int8+scale or bf16) ----
  {
    ushort_t (*Ep)[136] = (ushort_t(*)[136])smem;
#pragma unroll
    for (int mi = 0; mi < 4; ++mi)
#pragma unroll
      for (int ni = 0; ni < 4; ++ni)
#pragma unroll
        for (int r = 0; r < 4; ++r)
          Ep[wr * 64 + mi * 16 + l4 * 4 + r][wc * 64 + ni * 16 + l15] = f2bf(acc[mi][ni][r]);
    __syncthreads();
    int row = tid >> 1, half = tid & 1;
    int grow = row0 + row;
    if (grow < N_NODES) {
      if constexpr (sizeof(CT) == 1) {
        float vals[64];
        float amax = 0.f;
#pragma unroll
        for (int i = 0; i < 8; ++i) {
          us8 v = *(const us8*)&Ep[row][half * 64 + i * 8];
#pragma unroll
          for (int j = 0; j < 8; ++j) {
            float f = b2f((ushort_t)v[j]);
            vals[i * 8 + j] = f;
            amax = fmaxf(amax, fabsf(f));
          }
        }
        float inv = amax > 0.f ? 127.f / amax : 0.f;
        scales[grow * 4 + (col0 >> 6) + half] = amax * (1.f / 127.f);
        schar_t ob[64];
#pragma unroll
        for (int i = 0; i < 64; ++i)
          ob[i] = (schar_t)(int)rintf(vals[i] * inv);
#pragma unroll
        for (int i = 0; i < 4; ++i)
          *(us8*)&C[(size_t)grow * NCOL + col0 + half * 64 + i * 16] =
              *(const us8*)&ob[i * 16];
      } else {
#pragma unroll
        for (int i = 0; i < 8; ++i)
          *(us8*)&C[(size_t)grow * NCOL + col0 + half * 64 + i * 8] =
              *(const us8*)&Ep[row][half * 64 + i * 8];
      }
    }
  }
}

// ---------------- fused softmax + gather aggregation ----------------

// layer1: int8 messages + per-(node,head) scale; half-wave per edge, 4 in flight/half.
__global__ __launch_bounds__(256) void agg1(const int* __restrict__ rowptr,
                                            const int* __restrict__ colsrc,
                                            const schar_t* __restrict__ Hq,
                                            const float* __restrict__ Sc,
                                            const float* __restrict__ als,
                                            const float* __restrict__ ald,
                                            const float* __restrict__ b1,
                                            ushort_t* __restrict__ X2b) {
  int wave = threadIdx.x >> 6, lane = threadIdx.x & 63;
  int n = blockIdx.x * 4 + wave;
  if (n >= N_NODES) return;
  int half = lane >> 5, li = lane & 31, h = li >> 3;
  float ad = ald[n * 4 + h];
  int beg = rowptr[n], end = rowptr[n + 1];
  float a[8] = {};
  float s = 0.f;
  int i = beg + half;
  for (; i + 6 < end; i += 8) {
    int s0 = colsrc[i], s1 = colsrc[i + 2], s2 = colsrc[i + 4], s3 = colsrc[i + 6];
    float sc0 = als[s0 * 4 + h] + ad;
    float sc1 = als[s1 * 4 + h] + ad;
    float sc2 = als[s2 * 4 + h] + ad;
    float sc3 = als[s3 * 4 + h] + ad;
    float q0 = Sc[s0 * 4 + h], q1 = Sc[s1 * 4 + h], q2 = Sc[s2 * 4 + h], q3 = Sc[s3 * 4 + h];
    uint2 v0 = *(const uint2*)&Hq[(size_t)s0 * C1 + li * 8];
    uint2 v1 = *(const uint2*)&Hq[(size_t)s1 * C1 + li * 8];
    uint2 v2 = *(const uint2*)&Hq[(size_t)s2 * C1 + li * 8];
    uint2 v3 = *(const uint2*)&Hq[(size_t)s3 * C1 + li * 8];
    sc0 = sc0 > 0.f ? sc0 : NEG_SLOPE * sc0;
    sc1 = sc1 > 0.f ? sc1 : NEG_SLOPE * sc1;
    sc2 = sc2 > 0.f ? sc2 : NEG_SLOPE * sc2;
    sc3 = sc3 > 0.f ? sc3 : NEG_SLOPE * sc3;
    float w0 = __expf(sc0), w1 = __expf(sc1), w2 = __expf(sc2), w3 = __expf(sc3);
    s += (w0 + w1) + (w2 + w3);
    fma8q(w0 * q0, v0, a); fma8q(w1 * q1, v1, a);
    fma8q(w2 * q2, v2, a); fma8q(w3 * q3, v3, a);
  }
  for (; i + 2 < end; i += 4) {
    int s0 = colsrc[i], s1 = colsrc[i + 2];
    float sc0 = als[s0 * 4 + h] + ad;
    float sc1 = als[s1 * 4 + h] + ad;
    float q0 = Sc[s0 * 4 + h], q1 = Sc[s1 * 4 + h];
    uint2 v0 = *(const uint2*)&Hq[(size_t)s0 * C1 + li * 8];
    uint2 v1 = *(const uint2*)&Hq[(size_t)s1 * C1 + li * 8];
    sc0 = sc0 > 0.f ? sc0 : NEG_SLOPE * sc0;
    sc1 = sc1 > 0.f ? sc1 : NEG_SLOPE * sc1;
    float w0 = __expf(sc0), w1 = __expf(sc1);
    s += w0 + w1;
    fma8q(w0 * q0, v0, a); fma8q(w1 * q1, v1, a);
  }
  for (; i < end; i += 2) {
    int s0 = colsrc[i];
    float sc0 = als[s0 * 4 + h] + ad;
    float q0 = Sc[s0 * 4 + h];
    uint2 v0 = *(const uint2*)&Hq[(size_t)s0 * C1 + li * 8];
    sc0 = sc0 > 0.f ? sc0 : NEG_SLOPE * sc0;
    float w0 = __expf(sc0);
    s += w0;
    fma8q(w0 * q0, v0, a);
  }
#pragma unroll
  for (int j = 0; j < 8; ++j) a[j] += __shfl_xor(a[j], 32, 64);
  s += __shfl_xor(s, 32, 64);
  if (lane < 32) {
    float si = 1.f / s;
    int c = li * 8;
    float4 bb0 = *(const float4*)&b1[c];
    float4 bb1 = *(const float4*)&b1[c + 4];
    ushort_t o[8];
    o[0] = f2bf(fmaxf(a[0] * si + bb0.x, 0.f));
    o[1] = f2bf(fmaxf(a[1] * si + bb0.y, 0.f));
    o[2] = f2bf(fmaxf(a[2] * si + bb0.z, 0.f));
    o[3] = f2bf(fmaxf(a[3] * si + bb0.w, 0.f));
    o[4] = f2bf(fmaxf(a[4] * si + bb1.x, 0.f));
    o[5] = f2bf(fmaxf(a[5] * si + bb1.y, 0.f));
    o[6] = f2bf(fmaxf(a[6] * si + bb1.z, 0.f));
    o[7] = f2bf(fmaxf(a[7] * si + bb1.w, 0.f));
    *(us8*)&X2b[(size_t)n * C1 + c] = *(const us8*)o;
  }
}

// layer2: bf16 rows; quarter-wave per edge; 4 in flight per quarter.
__global__ __launch_bounds__(256) void agg2(const int* __restrict__ rowptr,
                                            const int* __restrict__ colsrc,
                                            const ushort_t* __restrict__ Hb,
                                            const float* __restrict__ als,
                                            const float* __restrict__ ald,
                                            const float* __restrict__ b2,
                                            float* __restrict__ out) {
  int wave = threadIdx.x >> 6, lane = threadIdx.x & 63;
  int n = blockIdx.x * 4 + wave;
  if (n >= N_NODES) return;
  int quarter = lane >> 4, li = lane & 15;
  float ad = ald[n];
  int beg = rowptr[n], end = rowptr[n + 1];
  float a[8] = {};
  float s = 0.f;
  int i = beg + quarter;
  for (; i + 12 < end; i += 16) {
    int s0 = colsrc[i], s1 = colsrc[i + 4], s2 = colsrc[i + 8], s3 = colsrc[i + 12];
    float sc0 = als[s0] + ad;
    float sc1 = als[s1] + ad;
    float sc2 = als[s2] + ad;
    float sc3 = als[s3] + ad;
    uint4 v0 = *(const uint4*)&Hb[(size_t)s0 * F_OUT + li * 8];
    uint4 v1 = *(const uint4*)&Hb[(size_t)s1 * F_OUT + li * 8];
    uint4 v2 = *(const uint4*)&Hb[(size_t)s2 * F_OUT + li * 8];
    uint4 v3 = *(const uint4*)&Hb[(size_t)s3 * F_OUT + li * 8];
    sc0 = sc0 > 0.f ? sc0 : NEG_SLOPE * sc0;
    sc1 = sc1 > 0.f ? sc1 : NEG_SLOPE * sc1;
    sc2 = sc2 > 0.f ? sc2 : NEG_SLOPE * sc2;
    sc3 = sc3 > 0.f ? sc3 : NEG_SLOPE * sc3;
    float w0 = __expf(sc0), w1 = __expf(sc1), w2 = __expf(sc2), w3 = __expf(sc3);
    s += (w0 + w1) + (w2 + w3);
    fma8v(w0, v0, a); fma8v(w1, v1, a); fma8v(w2, v2, a); fma8v(w3, v3, a);
  }
  for (; i + 4 < end; i += 8) {
    int s0 = colsrc[i], s1 = colsrc[i + 4];
    float sc0 = als[s0] + ad;
    float sc1 = als[s1] + ad;
    uint4 v0 = *(const uint4*)&Hb[(size_t)s0 * F_OUT + li * 8];
    uint4 v1 = *(const uint4*)&Hb[(size_t)s1 * F_OUT + li * 8];
    sc0 = sc0 > 0.f ? sc0 : NEG_SLOPE * sc0;
    sc1 = sc1 > 0.f ? sc1 : NEG_SLOPE * sc1;
    float w0 = __expf(sc0), w1 = __expf(sc1);
    s += w0 + w1;
    fma8v(w0, v0, a); fma8v(w1, v1, a);
  }
  for (; i < end; i += 4) {
    int s0 = colsrc[i];
    float sc0 = als[s0] + ad;
    uint4 v0 = *(const uint4*)&Hb[(size_t)s0 * F_OUT + li * 8];
    sc0 = sc0 > 0.f ? sc0 : NEG_SLOPE * sc0;
    float w0 = __expf(sc0);
    s += w0;
    fma8v(w0, v0, a);
  }
#pragma unroll
  for (int j = 0; j < 8; ++j) a[j] += __shfl_xor(a[j], 16, 64);
#pragma unroll
  for (int j = 0; j < 8; ++j) a[j] += __shfl_xor(a[j], 32, 64);
  s += __shfl_xor(s, 16, 64);
  s += __shfl_xor(s, 32, 64);
  if (lane < 16) {
    float si = 1.f / s;
    int c = li * 8;
    float4 bb0 = *(const float4*)&b2[c];
    float4 bb1 = *(const float4*)&b2[c + 4];
    float4 o0, o1;
    o0.x = a[0] * si + bb0.x; o0.y = a[1] * si + bb0.y;
    o0.z = a[2] * si + bb0.z; o0.w = a[3] * si + bb0.w;
    o1.x = a[4] * si + bb1.x; o1.y = a[5] * si + bb1.y;
    o1.z = a[6] * si + bb1.z; o1.w = a[7] * si + bb1.w;
    *(float4*)&out[(size_t)n * F_OUT + c] = o0;
    *(float4*)&out[(size_t)n * F_OUT + c + 4] = o1;
  }
}

// ---------------- launch ----------------

extern "C" void kernel_launch(void* const* d_in, const int* in_sizes, int n_in,
                              void* d_out, int out_size, void* d_ws, size_t ws_size,
                              hipStream_t stream) {
  const float* X   = (const float*)d_in[0];
  const int*   EI  = (const int*)d_in[1];
  const float* W1  = (const float*)d_in[2];
  const float* a1s = (const float*)d_in[3];
  const float* a1d = (const float*)d_in[4];
  const float* b1  = (const float*)d_in[5];
  const float* W2  = (const float*)d_in[6];
  const float* a2s = (const float*)d_in[7];
  const float* a2d = (const float*)d_in[8];
  const float* b2  = (const float*)d_in[9];
  float* out = (float*)d_out;

  char* ws = (char*)d_ws;
  size_t off = 0;
  auto alloc = [&](size_t bytes) -> void* {
    void* p = ws + off;
    off += (bytes + 255) & ~(size_t)255;
    return p;
  };
  // zero-init block first (single memset)
  int* bcnt       = (int*)alloc((size_t)NBUCK * BPAD * 4);   // 65KB padded counters
  int* bfill      = (int*)alloc((size_t)NBUCK * BPAD * 4);
  float* ALS2     = (float*)alloc((size_t)N_NODES * 4);
  float* ALD2     = (float*)alloc((size_t)N_NODES * 4);
  size_t zero_span = off;
  int* boff       = (int*)alloc((size_t)(NBUCK + 1) * 4);
  int* rowptr     = (int*)alloc((size_t)(N_NODES + 1) * 4);
  int* colsrc     = (int*)alloc((size_t)NET * 4);
  int2* pairs     = (int2*)alloc((size_t)NET * 8);           // 6.8MB
  ushort_t* W1t   = (ushort_t*)alloc((size_t)C1 * F_IN * 2);
  ushort_t* W2t   = (ushort_t*)alloc((size_t)F_OUT * C1 * 2);
  schar_t* H1q    = (schar_t*)alloc((size_t)N_NODES * C1);        // 12.8MB int8
  float* SC1      = (float*)alloc((size_t)N_NODES * HEADS * 4);   // 800KB scales
  float* ALS1     = (float*)alloc((size_t)N_NODES * HEADS * 4);
  float* ALD1     = (float*)alloc((size_t)N_NODES * HEADS * 4);
  ushort_t* X2b   = (ushort_t*)alloc((size_t)N_NODES * C1 * 2);
  ushort_t* H2b = (ushort_t*)H1q;  // H1 dead after agg1; 12.8MB each

  hipMemsetAsync(ws, 0, zero_span, stream);

  // bucketed CSR build (block-owned scatter runs)
  bucket_count<<<128, 256, 0, stream>>>(EI, bcnt);
  scan_buckets<<<1, 1024, 0, stream>>>(bcnt, boff);
  bucket_scatter_blocked<<<(NET + SCHUNK - 1) / SCHUNK, 1024, 0, stream>>>(EI, boff, bfill, pairs);
  build_csr<<<NBUCK, 256, 0, stream>>>(pairs, boff, rowptr, colsrc);

  // weight transposes (bf16), single launch
  transpose_both<<<(F_IN * C1 + C1 * F_OUT + 255) / 256, 256, 0, stream>>>(W1, W1t, W2, W2t);

  // layer 1 (A = fp32 X converted in staging; C = int8 + per-(node,head) scale)
  {
    dim3 grid(C1 / 128, (N_NODES + 127) / 128);
    gemm_mfma<F_IN, C1, 1, float, schar_t><<<grid, 256, 0, stream>>>(
        X, W1t, H1q, SC1, a1s, a1d, ALS1, ALD1);
  }
  agg1<<<(N_NODES + 3) / 4, 256, 0, stream>>>(rowptr, colsrc, H1q, SC1, ALS1, ALD1, b1, X2b);

  // layer 2 (bf16 throughout)
  {
    dim3 grid(F_OUT / 128, (N_NODES + 127) / 128);
    gemm_mfma<C1, F_OUT, 2, ushort_t, ushort_t><<<grid, 256, 0, stream>>>(
        X2b, W2t, H2b, nullptr, a2s, a2d, ALS2, ALD2);
  }
  agg2<<<(N_NODES + 3) / 4, 256, 0, stream>>>(rowptr, colsrc, H2b, ALS2, ALD2, b2, out);
}